// Round 6
// baseline (385.319 us; speedup 1.0000x reference)
//
#include <hip/hip_runtime.h>

namespace {
constexpr int N = 100000;
constexpr int E = 1600000;
constexpr int D = 128;
constexpr int U = 64;
constexpr int C = 40;
constexpr int C2 = C / 2;   // 20 packed bf16x2 words per row
constexpr int SLOTS = 64;   // padded CSR slots per node; deg ~ Poisson(16), P(>64) ~ 1e-15
constexpr int NB = (N + 255) / 256;  // 391 buckets of 256 nodes
constexpr int CAP = 4608;   // bucket capacity
constexpr int EPB = 16;
constexpr int TPB = 256;

// workspace layout (element offsets; 4-byte units)
constexpr size_t OFF_BCUR = 0;                               // 512 ints
constexpr size_t OFF_CUR = OFF_BCUR + 512;                   // N ints
constexpr size_t OFF_CSR = OFF_CUR + N;                      // 2*N*SLOTS ints
constexpr size_t OFF_BBUF = OFF_CSR + (size_t)2 * N * SLOTS; // NB*CAP*4 ints
// P1 (fp32) and P2B (bf16x2) overlay BBUF (dead after csr_build; stream-ordered)
constexpr size_t OFF_P1 = OFF_BBUF;                          // N*C floats
constexpr size_t OFF_P2B = OFF_P1 + (size_t)N * C + 16;      // N*C2 u32
constexpr size_t BBUF_INTS = (size_t)NB * CAP * 4;
constexpr size_t PROJ_INTS = (size_t)N * C + 16 + (size_t)N * C2 + 16;
constexpr size_t REGION = BBUF_INTS > PROJ_INTS ? BBUF_INTS : PROJ_INTS;
constexpr size_t OFF_RBF = OFF_BBUF + REGION;                // N*C2 u32
constexpr size_t OFF_G = OFF_RBF + (size_t)N * C2 + 16;      // 3*D*C floats
constexpr size_t OFF_BC = OFF_G + (size_t)3 * D * C;         // C floats
} // namespace

// ---- bf16 pack/unpack (RNE) ----
__device__ inline unsigned f2bf(float x) {
    unsigned u = __float_as_uint(x);
    return (u + 0x7fffu + ((u >> 16) & 1u)) >> 16;
}
__device__ inline unsigned pack_bf2(float a, float b) { return f2bf(a) | (f2bf(b) << 16); }
__device__ inline float2 unpack_bf2(unsigned v) {
    return make_float2(__uint_as_float(v << 16), __uint_as_float(v & 0xffff0000u));
}

// ---- fold weights: G0 = (W0-W2)@Wd ; G1 = -(W1@Wd) ; G2 = 2*(W2@Wd) ; bc = b@Wd + bd
__global__ void prep_weights(const float* __restrict__ W, const float* __restrict__ b,
                             const float* __restrict__ Wd, const float* __restrict__ bd,
                             float* __restrict__ G, float* __restrict__ bc) {
    int t = blockIdx.x * blockDim.x + threadIdx.x;
    if (t < 3 * D * C) {
        int k = t / (D * C);
        int r = t % (D * C);
        int d = r / C;
        int c = r % C;
        const float* Wk = W + (size_t)k * D * U + (size_t)d * U;
        float s = 0.f;
        for (int u = 0; u < U; ++u) s += Wk[u] * Wd[u * C + c];
        float outv;
        if (k == 0) {
            const float* W2 = W + (size_t)2 * D * U + (size_t)d * U;
            float s2 = 0.f;
            for (int u = 0; u < U; ++u) s2 += W2[u] * Wd[u * C + c];
            outv = s - s2;
        } else if (k == 1) {
            outv = -s;
        } else {
            outv = 2.f * s;
        }
        G[t] = outv;
    } else if (t < 3 * D * C + C) {
        int c = t - 3 * D * C;
        float s = bd[c];
        for (int u = 0; u < U; ++u) s += b[u] * Wd[u * C + c];
        bc[c] = s;
    }
}

// Pass C: two-level counting scatter into per-bucket contiguous regions.
__global__ __launch_bounds__(TPB) void bucket_scatter(const int* __restrict__ src,
                                                      const int* __restrict__ dst,
                                                      const float* __restrict__ ew,
                                                      int* __restrict__ bcur,
                                                      int4* __restrict__ bbuf) {
    __shared__ int hist[NB];
    __shared__ int base[NB];
    int t = threadIdx.x;
    for (int i = t; i < NB; i += TPB) hist[i] = 0;
    __syncthreads();

    size_t e0 = (size_t)blockIdx.x * (TPB * EPB);
    int ms[EPB], md[EPB], mw[EPB], mr[EPB];
#pragma unroll
    for (int k = 0; k < EPB; ++k) {
        size_t e = e0 + (size_t)k * TPB + t;
        if (e < E) {
            ms[k] = src[e];
            md[k] = dst[e];
            mw[k] = __float_as_int(ew[e]);
            mr[k] = atomicAdd(&hist[md[k] >> 8], 1);
        } else {
            md[k] = -1;
        }
    }
    __syncthreads();
    for (int i = t; i < NB; i += TPB) {
        int c = hist[i];
        base[i] = c ? atomicAdd(&bcur[i], c) : 0;
    }
    __syncthreads();
#pragma unroll
    for (int k = 0; k < EPB; ++k) {
        if (md[k] >= 0) {
            int bkt = md[k] >> 8;
            int slot = base[bkt] + mr[k];
            if (slot < CAP) bbuf[(size_t)bkt * CAP + slot] = make_int4(ms[k], mw[k], md[k], 0);
        }
    }
}

// Pass D: one block per bucket; LDS-only slotting.
__global__ __launch_bounds__(256) void csr_build(const int* __restrict__ bcur,
                                                 const int4* __restrict__ bbuf,
                                                 int* __restrict__ cur,
                                                 int2* __restrict__ csr) {
    __shared__ int lcur[256];
    int b = blockIdx.x;
    int t = threadIdx.x;
    lcur[t] = 0;
    __syncthreads();
    int cnt = min(bcur[b], CAP);
    for (int i = t; i < cnt; i += 256) {
        int4 r = bbuf[(size_t)b * CAP + i];
        int slot = atomicAdd(&lcur[r.z & 255], 1);
        if (slot < SLOTS) csr[((size_t)r.z << 6) + slot] = make_int2(r.x, r.y);
    }
    __syncthreads();
    int node = (b << 8) + t;
    if (node < N) cur[node] = min(lcur[t], SLOTS);
}

// proj_all: one pass over x -> out = x@G0 + bc (fp32) ; P1 = x@G1 (fp32) ; P2B = bf16(x@G2)
__global__ __launch_bounds__(256) void proj_all(const float* __restrict__ X,
                                                const float* __restrict__ G,
                                                const float* __restrict__ bc,
                                                float* __restrict__ out,
                                                float* __restrict__ P1,
                                                unsigned* __restrict__ P2B) {
    __shared__ __align__(16) float gs[3 * D * C + C];  // 61.6 KB
    for (int i = threadIdx.x; i < 3 * D * C + C; i += 256)
        gs[i] = (i < 3 * D * C) ? G[i] : bc[i - 3 * D * C];
    __syncthreads();

    int n = blockIdx.x * blockDim.x + threadIdx.x;
    if (n >= N) return;

    float4 a0[10], a1[10], a2[10];
#pragma unroll
    for (int q = 0; q < 10; ++q) {
        a0[q] = ((const float4*)(gs + 3 * D * C))[q];
        a1[q] = make_float4(0.f, 0.f, 0.f, 0.f);
        a2[q] = make_float4(0.f, 0.f, 0.f, 0.f);
    }

    const float4* T4 = (const float4*)(X + (size_t)n * D);
    for (int dq = 0; dq < D / 4; ++dq) {
        float4 v = T4[dq];
#pragma unroll
        for (int j = 0; j < 4; ++j) {
            float vv = (j == 0 ? v.x : (j == 1 ? v.y : (j == 2 ? v.z : v.w)));
            int d = dq * 4 + j;
            const float4* g0 = (const float4*)(gs + d * C);
            const float4* g1 = (const float4*)(gs + D * C + d * C);
            const float4* g2 = (const float4*)(gs + 2 * D * C + d * C);
#pragma unroll
            for (int q = 0; q < 10; ++q) {
                float4 g = g0[q];
                a0[q].x += vv * g.x; a0[q].y += vv * g.y;
                a0[q].z += vv * g.z; a0[q].w += vv * g.w;
                float4 h = g1[q];
                a1[q].x += vv * h.x; a1[q].y += vv * h.y;
                a1[q].z += vv * h.z; a1[q].w += vv * h.w;
                float4 e = g2[q];
                a2[q].x += vv * e.x; a2[q].y += vv * e.y;
                a2[q].z += vv * e.z; a2[q].w += vv * e.w;
            }
        }
    }

    float4* o4 = (float4*)(out + (size_t)n * C);
    float4* p4 = (float4*)(P1 + (size_t)n * C);
#pragma unroll
    for (int q = 0; q < 10; ++q) { o4[q] = a0[q]; p4[q] = a1[q]; }

    uint4* pb = (uint4*)(P2B + (size_t)n * C2);  // 80B rows, 16B-aligned
#pragma unroll
    for (int q = 0; q < 5; ++q) {
        uint4 w;
        w.x = pack_bf2(a2[2 * q].x, a2[2 * q].y);
        w.y = pack_bf2(a2[2 * q].z, a2[2 * q].w);
        w.z = pack_bf2(a2[2 * q + 1].x, a2[2 * q + 1].y);
        w.w = pack_bf2(a2[2 * q + 1].z, a2[2 * q + 1].w);
        pb[q] = w;
    }
}

// gather SpMM on bf16-packed 40-dim rows, fused rw-norm and add:
//   Y[n] = Add[n] + (sum_e w_e * Xg[src_e]) / max(sum_e w_e, 1e-12)
// one wave/node; lane l<20 owns packed cols {2l, 2l+1}. OUT_BF selects bf16 or fp32 output.
template <bool OUT_BF>
__global__ __launch_bounds__(256) void spmm40bf(const int* __restrict__ cur,
                                                const int2* __restrict__ csr,
                                                const unsigned* __restrict__ Xg,
                                                const float* __restrict__ Add,
                                                void* __restrict__ Yv) {
    int wid = (blockIdx.x * blockDim.x + threadIdx.x) >> 6;
    int lane = threadIdx.x & 63;
    if (wid >= N) return;
    int c = cur[wid];
    int2 p = make_int2(0, 0);
    if (lane < c) p = csr[((size_t)wid << 6) + lane];
    float myw = __int_as_float(p.y);
    float deg = myw;
#pragma unroll
    for (int off = 32; off > 0; off >>= 1) deg += __shfl_xor(deg, off);
    float rdeg = 1.f / fmaxf(deg, 1e-12f);
    float2 acc = make_float2(0.f, 0.f);
    for (int j = 0; j < c; ++j) {
        int col = __shfl(p.x, j);
        float w = __shfl(myw, j);
        if (lane < C2) {
            float2 v = unpack_bf2(Xg[(size_t)col * C2 + lane]);
            acc.x = fmaf(w, v.x, acc.x);
            acc.y = fmaf(w, v.y, acc.y);
        }
    }
    if (lane < C2) {
        float2 ad = ((const float2*)Add)[(size_t)wid * C2 + lane];
        float ox = fmaf(acc.x, rdeg, ad.x);
        float oy = fmaf(acc.y, rdeg, ad.y);
        if (OUT_BF)
            ((unsigned*)Yv)[(size_t)wid * C2 + lane] = pack_bf2(ox, oy);
        else
            ((float2*)Yv)[(size_t)wid * C2 + lane] = make_float2(ox, oy);
    }
}

extern "C" void kernel_launch(void* const* d_in, const int* in_sizes, int n_in,
                              void* d_out, int out_size, void* d_ws, size_t ws_size,
                              hipStream_t stream) {
    const float* x = (const float*)d_in[0];
    const int* ei = (const int*)d_in[1];   // (2, E): src = ei, dst = ei + E
    const float* ew = (const float*)d_in[2];
    const float* W = (const float*)d_in[3];
    const float* b = (const float*)d_in[4];
    const float* Wd = (const float*)d_in[5];
    const float* bd = (const float*)d_in[6];
    float* out = (float*)d_out;

    const int* src = ei;
    const int* dst = ei + E;

    float* ws = (float*)d_ws;
    int* bcur = (int*)(ws + OFF_BCUR);
    int* cur = (int*)(ws + OFF_CUR);
    int2* csr = (int2*)(ws + OFF_CSR);
    int4* bbuf = (int4*)(ws + OFF_BBUF);
    float* P1 = ws + OFF_P1;
    unsigned* P2B = (unsigned*)(ws + OFF_P2B);
    unsigned* Rbf = (unsigned*)(ws + OFF_RBF);
    float* G = ws + OFF_G;
    float* bc = ws + OFF_BC;

    // zero bucket cursors only
    hipMemsetAsync((char*)d_ws + OFF_BCUR * sizeof(int), 0, 512 * sizeof(int), stream);

    prep_weights<<<(3 * D * C + C + 255) / 256, 256, 0, stream>>>(W, b, Wd, bd, G, bc);

    // two-level counting sort -> padded CSR
    bucket_scatter<<<(E + TPB * EPB - 1) / (TPB * EPB), TPB, 0, stream>>>(src, dst, ew, bcur, bbuf);
    csr_build<<<NB, 256, 0, stream>>>(bcur, bbuf, cur, csr);

    // out = x@G0 + bc ; P1 = x@G1 ; P2B = bf16(x@G2)   (P1/P2B overwrite bbuf — dead by now)
    proj_all<<<(N + 255) / 256, 256, 0, stream>>>(x, G, bc, out, P1, P2B);

    // Rbf = bf16(P1 + A_hat @ P2)
    spmm40bf<true><<<((size_t)N * 64 + 255) / 256, 256, 0, stream>>>(cur, csr, P2B, P1, Rbf);
    // out += A_hat @ R
    spmm40bf<false><<<((size_t)N * 64 + 255) / 256, 256, 0, stream>>>(cur, csr, Rbf, out, out);
}

// Round 7
// 277.925 us; speedup vs baseline: 1.3864x; 1.3864x over previous
//
#include <hip/hip_runtime.h>

namespace {
constexpr int N = 100000;
constexpr int E = 1600000;
constexpr int D = 128;
constexpr int U = 64;
constexpr int C = 40;
constexpr int C2 = C / 2;   // 20 packed bf16x2 words per row
constexpr int RP = 32;      // padded row stride in u32 (128 B) -> 1 cache line per gather
constexpr int SLOTS = 64;   // padded CSR slots per node; deg ~ Poisson(16), P(>64) ~ 1e-15
constexpr int NB = (N + 255) / 256;  // 391 buckets of 256 nodes
constexpr int CAP = 4608;   // bucket capacity
constexpr int EPB = 16;
constexpr int TPB = 256;

// workspace layout (element offsets; 4-byte units; keep 128B (32-elt) alignment)
constexpr size_t OFF_BCUR = 0;                               // 512 ints
constexpr size_t OFF_CUR = OFF_BCUR + 512;                   // N ints
constexpr size_t OFF_CSR = OFF_CUR + N;                      // 2*N*SLOTS ints
constexpr size_t OFF_BBUF = OFF_CSR + (size_t)2 * N * SLOTS; // NB*CAP*4 ints
// P1 (fp32, stride C) and P2B (bf16x2, stride RP) overlay BBUF (dead after csr_build)
constexpr size_t OFF_P1 = OFF_BBUF;                          // N*C floats
constexpr size_t OFF_P2B = OFF_P1 + (size_t)N * C + 32;      // N*RP u32
constexpr size_t BBUF_INTS = (size_t)NB * CAP * 4;
constexpr size_t PROJ_INTS = (size_t)N * C + 32 + (size_t)N * RP;
constexpr size_t REGION = BBUF_INTS > PROJ_INTS ? BBUF_INTS : PROJ_INTS;
constexpr size_t OFF_RBF = OFF_BBUF + REGION;                // N*RP u32
constexpr size_t OFF_G = OFF_RBF + (size_t)N * RP;           // 3*D*C floats
constexpr size_t OFF_BC = OFF_G + (size_t)3 * D * C;         // C floats
} // namespace

// ---- bf16 pack/unpack (RNE) ----
__device__ inline unsigned f2bf(float x) {
    unsigned u = __float_as_uint(x);
    return (u + 0x7fffu + ((u >> 16) & 1u)) >> 16;
}
__device__ inline unsigned pack_bf2(float a, float b) { return f2bf(a) | (f2bf(b) << 16); }
__device__ inline float2 unpack_bf2(unsigned v) {
    return make_float2(__uint_as_float(v << 16), __uint_as_float(v & 0xffff0000u));
}

// ---- fold weights: G0 = (W0-W2)@Wd ; G1 = -(W1@Wd) ; G2 = 2*(W2@Wd) ; bc = b@Wd + bd
__global__ void prep_weights(const float* __restrict__ W, const float* __restrict__ b,
                             const float* __restrict__ Wd, const float* __restrict__ bd,
                             float* __restrict__ G, float* __restrict__ bc) {
    int t = blockIdx.x * blockDim.x + threadIdx.x;
    if (t < 3 * D * C) {
        int k = t / (D * C);
        int r = t % (D * C);
        int d = r / C;
        int c = r % C;
        const float* Wk = W + (size_t)k * D * U + (size_t)d * U;
        float s = 0.f;
        for (int u = 0; u < U; ++u) s += Wk[u] * Wd[u * C + c];
        float outv;
        if (k == 0) {
            const float* W2 = W + (size_t)2 * D * U + (size_t)d * U;
            float s2 = 0.f;
            for (int u = 0; u < U; ++u) s2 += W2[u] * Wd[u * C + c];
            outv = s - s2;
        } else if (k == 1) {
            outv = -s;
        } else {
            outv = 2.f * s;
        }
        G[t] = outv;
    } else if (t < 3 * D * C + C) {
        int c = t - 3 * D * C;
        float s = bd[c];
        for (int u = 0; u < U; ++u) s += b[u] * Wd[u * C + c];
        bc[c] = s;
    }
}

// Pass C: two-level counting scatter into per-bucket contiguous regions.
__global__ __launch_bounds__(TPB) void bucket_scatter(const int* __restrict__ src,
                                                      const int* __restrict__ dst,
                                                      const float* __restrict__ ew,
                                                      int* __restrict__ bcur,
                                                      int4* __restrict__ bbuf) {
    __shared__ int hist[NB];
    __shared__ int base[NB];
    int t = threadIdx.x;
    for (int i = t; i < NB; i += TPB) hist[i] = 0;
    __syncthreads();

    size_t e0 = (size_t)blockIdx.x * (TPB * EPB);
    int ms[EPB], md[EPB], mw[EPB], mr[EPB];
#pragma unroll
    for (int k = 0; k < EPB; ++k) {
        size_t e = e0 + (size_t)k * TPB + t;
        if (e < E) {
            ms[k] = src[e];
            md[k] = dst[e];
            mw[k] = __float_as_int(ew[e]);
            mr[k] = atomicAdd(&hist[md[k] >> 8], 1);
        } else {
            md[k] = -1;
        }
    }
    __syncthreads();
    for (int i = t; i < NB; i += TPB) {
        int c = hist[i];
        base[i] = c ? atomicAdd(&bcur[i], c) : 0;
    }
    __syncthreads();
#pragma unroll
    for (int k = 0; k < EPB; ++k) {
        if (md[k] >= 0) {
            int bkt = md[k] >> 8;
            int slot = base[bkt] + mr[k];
            if (slot < CAP) bbuf[(size_t)bkt * CAP + slot] = make_int4(ms[k], mw[k], md[k], 0);
        }
    }
}

// Pass D: one block per bucket; LDS-only slotting.
__global__ __launch_bounds__(256) void csr_build(const int* __restrict__ bcur,
                                                 const int4* __restrict__ bbuf,
                                                 int* __restrict__ cur,
                                                 int2* __restrict__ csr) {
    __shared__ int lcur[256];
    int b = blockIdx.x;
    int t = threadIdx.x;
    lcur[t] = 0;
    __syncthreads();
    int cnt = min(bcur[b], CAP);
    for (int i = t; i < cnt; i += 256) {
        int4 r = bbuf[(size_t)b * CAP + i];
        int slot = atomicAdd(&lcur[r.z & 255], 1);
        if (slot < SLOTS) csr[((size_t)r.z << 6) + slot] = make_int2(r.x, r.y);
    }
    __syncthreads();
    int node = (b << 8) + t;
    if (node < N) cur[node] = min(lcur[t], SLOTS);
}

// projA: out[n] = x[n] @ G0 + bc   (20.8 KB LDS -> good occupancy)
__global__ __launch_bounds__(256) void projA(const float* __restrict__ X,
                                             const float* __restrict__ G,
                                             const float* __restrict__ bc,
                                             float* __restrict__ out) {
    __shared__ __align__(16) float gs[D * C + C];
    for (int i = threadIdx.x; i < D * C + C; i += 256)
        gs[i] = (i < D * C) ? G[i] : bc[i - D * C];
    __syncthreads();

    int n = blockIdx.x * blockDim.x + threadIdx.x;
    if (n >= N) return;

    float4 acc[10];
#pragma unroll
    for (int q = 0; q < 10; ++q) acc[q] = ((const float4*)(gs + D * C))[q];

    const float4* T4 = (const float4*)(X + (size_t)n * D);
    for (int dq = 0; dq < D / 4; ++dq) {
        float4 v = T4[dq];
#pragma unroll
        for (int j = 0; j < 4; ++j) {
            float vv = (j == 0 ? v.x : (j == 1 ? v.y : (j == 2 ? v.z : v.w)));
            const float4* g4 = (const float4*)(gs + (dq * 4 + j) * C);
#pragma unroll
            for (int q = 0; q < 10; ++q) {
                float4 g = g4[q];
                acc[q].x += vv * g.x;
                acc[q].y += vv * g.y;
                acc[q].z += vv * g.z;
                acc[q].w += vv * g.w;
            }
        }
    }
    float4* o4 = (float4*)(out + (size_t)n * C);
#pragma unroll
    for (int q = 0; q < 10; ++q) o4[q] = acc[q];
}

// projB: P1[n] = x[n]@G1 (fp32, stride C) ; P2B[n] = bf16(x[n]@G2) (stride RP, 128B rows)
__global__ __launch_bounds__(256) void projB(const float* __restrict__ X,
                                             const float* __restrict__ G,
                                             float* __restrict__ P1,
                                             unsigned* __restrict__ P2B) {
    __shared__ __align__(16) float gs[2 * D * C];  // 41 KB -> 3 blocks/CU
    for (int i = threadIdx.x; i < 2 * D * C; i += 256) gs[i] = G[D * C + i];
    __syncthreads();

    int n = blockIdx.x * blockDim.x + threadIdx.x;
    if (n >= N) return;

    float4 a1[10], a2[10];
#pragma unroll
    for (int q = 0; q < 10; ++q) {
        a1[q] = make_float4(0.f, 0.f, 0.f, 0.f);
        a2[q] = make_float4(0.f, 0.f, 0.f, 0.f);
    }

    const float4* T4 = (const float4*)(X + (size_t)n * D);
    for (int dq = 0; dq < D / 4; ++dq) {
        float4 v = T4[dq];
#pragma unroll
        for (int j = 0; j < 4; ++j) {
            float vv = (j == 0 ? v.x : (j == 1 ? v.y : (j == 2 ? v.z : v.w)));
            const float4* g1 = (const float4*)(gs + (dq * 4 + j) * C);
            const float4* g2 = (const float4*)(gs + D * C + (dq * 4 + j) * C);
#pragma unroll
            for (int q = 0; q < 10; ++q) {
                float4 g = g1[q];
                a1[q].x += vv * g.x; a1[q].y += vv * g.y;
                a1[q].z += vv * g.z; a1[q].w += vv * g.w;
                float4 h = g2[q];
                a2[q].x += vv * h.x; a2[q].y += vv * h.y;
                a2[q].z += vv * h.z; a2[q].w += vv * h.w;
            }
        }
    }
    float4* p4 = (float4*)(P1 + (size_t)n * C);
#pragma unroll
    for (int q = 0; q < 10; ++q) p4[q] = a1[q];

    uint4* pb = (uint4*)(P2B + ((size_t)n << 5));  // 128B-aligned padded rows
#pragma unroll
    for (int q = 0; q < 5; ++q) {
        uint4 w;
        w.x = pack_bf2(a2[2 * q].x, a2[2 * q].y);
        w.y = pack_bf2(a2[2 * q].z, a2[2 * q].w);
        w.z = pack_bf2(a2[2 * q + 1].x, a2[2 * q + 1].y);
        w.w = pack_bf2(a2[2 * q + 1].z, a2[2 * q + 1].w);
        pb[q] = w;
    }
}

// gather SpMM on bf16-packed padded rows, fused rw-norm and add:
//   Y[n] = Add[n] + (sum_e w_e * Xg[src_e]) / max(sum_e w_e, 1e-12)
// one wave/node. Half-split: lanes 0-31 process even edges, 32-63 odd edges
// (each half's lanes 0-19 load one 80B row within one 128B line) -> 2x MLP.
template <bool OUT_BF>
__global__ __launch_bounds__(256) void spmm40bf(const int* __restrict__ cur,
                                                const int2* __restrict__ csr,
                                                const unsigned* __restrict__ Xg,
                                                const float* __restrict__ Add,
                                                void* __restrict__ Yv) {
    int wid = (blockIdx.x * blockDim.x + threadIdx.x) >> 6;
    int lane = threadIdx.x & 63;
    if (wid >= N) return;
    int c = cur[wid];
    int2 p = make_int2(0, 0);
    if (lane < c) p = csr[((size_t)wid << 6) + lane];
    float myw = __int_as_float(p.y);
    float deg = myw;
#pragma unroll
    for (int off = 32; off > 0; off >>= 1) deg += __shfl_xor(deg, off);
    float rdeg = 1.f / fmaxf(deg, 1e-12f);

    int half = lane >> 5;
    int l2 = lane & 31;
    float2 acc = make_float2(0.f, 0.f);
    for (int j0 = 0; j0 < c; j0 += 2) {
        int j = j0 + half;
        int js = min(j, c - 1);
        int col = __shfl(p.x, js);
        float w = __shfl(myw, js);
        if (j < c && l2 < C2) {
            float2 v = unpack_bf2(Xg[((size_t)col << 5) + l2]);
            acc.x = fmaf(w, v.x, acc.x);
            acc.y = fmaf(w, v.y, acc.y);
        }
    }
    acc.x += __shfl_xor(acc.x, 32);
    acc.y += __shfl_xor(acc.y, 32);

    if (lane < C2) {
        float2 ad = ((const float2*)Add)[(size_t)wid * C2 + lane];
        float ox = fmaf(acc.x, rdeg, ad.x);
        float oy = fmaf(acc.y, rdeg, ad.y);
        if (OUT_BF)
            ((unsigned*)Yv)[((size_t)wid << 5) + lane] = pack_bf2(ox, oy);
        else
            ((float2*)Yv)[(size_t)wid * C2 + lane] = make_float2(ox, oy);
    }
}

extern "C" void kernel_launch(void* const* d_in, const int* in_sizes, int n_in,
                              void* d_out, int out_size, void* d_ws, size_t ws_size,
                              hipStream_t stream) {
    const float* x = (const float*)d_in[0];
    const int* ei = (const int*)d_in[1];   // (2, E): src = ei, dst = ei + E
    const float* ew = (const float*)d_in[2];
    const float* W = (const float*)d_in[3];
    const float* b = (const float*)d_in[4];
    const float* Wd = (const float*)d_in[5];
    const float* bd = (const float*)d_in[6];
    float* out = (float*)d_out;

    const int* src = ei;
    const int* dst = ei + E;

    float* ws = (float*)d_ws;
    int* bcur = (int*)(ws + OFF_BCUR);
    int* cur = (int*)(ws + OFF_CUR);
    int2* csr = (int2*)(ws + OFF_CSR);
    int4* bbuf = (int4*)(ws + OFF_BBUF);
    float* P1 = ws + OFF_P1;
    unsigned* P2B = (unsigned*)(ws + OFF_P2B);
    unsigned* Rbf = (unsigned*)(ws + OFF_RBF);
    float* G = ws + OFF_G;
    float* bc = ws + OFF_BC;

    // zero bucket cursors only
    hipMemsetAsync((char*)d_ws + OFF_BCUR * sizeof(int), 0, 512 * sizeof(int), stream);

    prep_weights<<<(3 * D * C + C + 255) / 256, 256, 0, stream>>>(W, b, Wd, bd, G, bc);

    // two-level counting sort -> padded CSR
    bucket_scatter<<<(E + TPB * EPB - 1) / (TPB * EPB), TPB, 0, stream>>>(src, dst, ew, bcur, bbuf);
    csr_build<<<NB, 256, 0, stream>>>(bcur, bbuf, cur, csr);

    // out = x@G0 + bc ; P1 = x@G1 ; P2B = bf16(x@G2)  (P1/P2B overwrite bbuf — dead by now)
    projA<<<(N + 255) / 256, 256, 0, stream>>>(x, G, bc, out);
    projB<<<(N + 255) / 256, 256, 0, stream>>>(x, G, P1, P2B);

    // Rbf = bf16(P1 + A_hat @ P2)
    spmm40bf<true><<<((size_t)N * 64 + 255) / 256, 256, 0, stream>>>(cur, csr, P2B, P1, Rbf);
    // out += A_hat @ R
    spmm40bf<false><<<((size_t)N * 64 + 255) / 256, 256, 0, stream>>>(cur, csr, Rbf, out, out);
}

// Round 8
// 224.554 us; speedup vs baseline: 1.7159x; 1.2377x over previous
//
#include <hip/hip_runtime.h>

namespace {
constexpr int N = 100000;
constexpr int E = 1600000;
constexpr int D = 128;
constexpr int U = 64;
constexpr int C = 40;
constexpr int C2 = C / 2;   // 20 packed bf16x2 words per row
constexpr int RP = 32;      // padded row stride in u32 (128 B)
constexpr int SLOTS = 64;   // padded CSR slots per node; deg ~ Poisson(16), P(>64) ~ 1e-15
constexpr int NB = (N + 255) / 256;  // 391 buckets of 256 nodes
constexpr int CAP = 4608;   // bucket capacity
constexpr int EPB = 16;
constexpr int TPB = 256;

// workspace layout (element offsets; 4-byte units; keep 128B (32-elt) alignment)
constexpr size_t OFF_BCUR = 0;                               // 512 ints
constexpr size_t OFF_CUR = OFF_BCUR + 512;                   // N ints
constexpr size_t OFF_CSR = OFF_CUR + N;                      // 2*N*SLOTS ints
constexpr size_t OFF_BBUF = OFF_CSR + (size_t)2 * N * SLOTS; // NB*CAP*4 ints
// P1 (fp32, stride C) and P2B (bf16x2, stride RP) overlay BBUF (dead after csr_build)
constexpr size_t OFF_P1 = OFF_BBUF;                          // N*C floats
constexpr size_t OFF_P2B = OFF_P1 + (size_t)N * C + 32;      // N*RP u32
constexpr size_t BBUF_INTS = (size_t)NB * CAP * 4;
constexpr size_t PROJ_INTS = (size_t)N * C + 32 + (size_t)N * RP;
constexpr size_t REGION = BBUF_INTS > PROJ_INTS ? BBUF_INTS : PROJ_INTS;
constexpr size_t OFF_RBF = OFF_BBUF + REGION;                // N*RP u32
constexpr size_t OFF_G = OFF_RBF + (size_t)N * RP;           // 3*D*C floats
constexpr size_t OFF_BC = OFF_G + (size_t)3 * D * C;         // C floats
} // namespace

// ---- bf16 pack/unpack (RNE) ----
__device__ inline unsigned f2bf(float x) {
    unsigned u = __float_as_uint(x);
    return (u + 0x7fffu + ((u >> 16) & 1u)) >> 16;
}
__device__ inline unsigned pack_bf2(float a, float b) { return f2bf(a) | (f2bf(b) << 16); }
__device__ inline float2 unpack_bf2(unsigned v) {
    return make_float2(__uint_as_float(v << 16), __uint_as_float(v & 0xffff0000u));
}

// ---- fold weights: G0 = (W0-W2)@Wd ; G1 = -(W1@Wd) ; G2 = 2*(W2@Wd) ; bc = b@Wd + bd
__global__ void prep_weights(const float* __restrict__ W, const float* __restrict__ b,
                             const float* __restrict__ Wd, const float* __restrict__ bd,
                             float* __restrict__ G, float* __restrict__ bc) {
    int t = blockIdx.x * blockDim.x + threadIdx.x;
    if (t < 3 * D * C) {
        int k = t / (D * C);
        int r = t % (D * C);
        int d = r / C;
        int c = r % C;
        const float* Wk = W + (size_t)k * D * U + (size_t)d * U;
        float s = 0.f;
        for (int u = 0; u < U; ++u) s += Wk[u] * Wd[u * C + c];
        float outv;
        if (k == 0) {
            const float* W2 = W + (size_t)2 * D * U + (size_t)d * U;
            float s2 = 0.f;
            for (int u = 0; u < U; ++u) s2 += W2[u] * Wd[u * C + c];
            outv = s - s2;
        } else if (k == 1) {
            outv = -s;
        } else {
            outv = 2.f * s;
        }
        G[t] = outv;
    } else if (t < 3 * D * C + C) {
        int c = t - 3 * D * C;
        float s = bd[c];
        for (int u = 0; u < U; ++u) s += b[u] * Wd[u * C + c];
        bc[c] = s;
    }
}

// Pass C: two-level counting scatter into per-bucket contiguous regions.
__global__ __launch_bounds__(TPB) void bucket_scatter(const int* __restrict__ src,
                                                      const int* __restrict__ dst,
                                                      const float* __restrict__ ew,
                                                      int* __restrict__ bcur,
                                                      int4* __restrict__ bbuf) {
    __shared__ int hist[NB];
    __shared__ int base[NB];
    int t = threadIdx.x;
    for (int i = t; i < NB; i += TPB) hist[i] = 0;
    __syncthreads();

    size_t e0 = (size_t)blockIdx.x * (TPB * EPB);
    int ms[EPB], md[EPB], mw[EPB], mr[EPB];
#pragma unroll
    for (int k = 0; k < EPB; ++k) {
        size_t e = e0 + (size_t)k * TPB + t;
        if (e < E) {
            ms[k] = src[e];
            md[k] = dst[e];
            mw[k] = __float_as_int(ew[e]);
            mr[k] = atomicAdd(&hist[md[k] >> 8], 1);
        } else {
            md[k] = -1;
        }
    }
    __syncthreads();
    for (int i = t; i < NB; i += TPB) {
        int c = hist[i];
        base[i] = c ? atomicAdd(&bcur[i], c) : 0;
    }
    __syncthreads();
#pragma unroll
    for (int k = 0; k < EPB; ++k) {
        if (md[k] >= 0) {
            int bkt = md[k] >> 8;
            int slot = base[bkt] + mr[k];
            if (slot < CAP) bbuf[(size_t)bkt * CAP + slot] = make_int4(ms[k], mw[k], md[k], 0);
        }
    }
}

// Pass D: one block per bucket; LDS-only slotting.
__global__ __launch_bounds__(256) void csr_build(const int* __restrict__ bcur,
                                                 const int4* __restrict__ bbuf,
                                                 int* __restrict__ cur,
                                                 int2* __restrict__ csr) {
    __shared__ int lcur[256];
    int b = blockIdx.x;
    int t = threadIdx.x;
    lcur[t] = 0;
    __syncthreads();
    int cnt = min(bcur[b], CAP);
    for (int i = t; i < cnt; i += 256) {
        int4 r = bbuf[(size_t)b * CAP + i];
        int slot = atomicAdd(&lcur[r.z & 255], 1);
        if (slot < SLOTS) csr[((size_t)r.z << 6) + slot] = make_int2(r.x, r.y);
    }
    __syncthreads();
    int node = (b << 8) + t;
    if (node < N) cur[node] = min(lcur[t], SLOTS);
}

// projA: out[n] = x[n] @ G0 + bc   (20.8 KB LDS -> good occupancy)
__global__ __launch_bounds__(256) void projA(const float* __restrict__ X,
                                             const float* __restrict__ G,
                                             const float* __restrict__ bc,
                                             float* __restrict__ out) {
    __shared__ __align__(16) float gs[D * C + C];
    for (int i = threadIdx.x; i < D * C + C; i += 256)
        gs[i] = (i < D * C) ? G[i] : bc[i - D * C];
    __syncthreads();

    int n = blockIdx.x * blockDim.x + threadIdx.x;
    if (n >= N) return;

    float4 acc[10];
#pragma unroll
    for (int q = 0; q < 10; ++q) acc[q] = ((const float4*)(gs + D * C))[q];

    const float4* T4 = (const float4*)(X + (size_t)n * D);
    for (int dq = 0; dq < D / 4; ++dq) {
        float4 v = T4[dq];
#pragma unroll
        for (int j = 0; j < 4; ++j) {
            float vv = (j == 0 ? v.x : (j == 1 ? v.y : (j == 2 ? v.z : v.w)));
            const float4* g4 = (const float4*)(gs + (dq * 4 + j) * C);
#pragma unroll
            for (int q = 0; q < 10; ++q) {
                float4 g = g4[q];
                acc[q].x += vv * g.x;
                acc[q].y += vv * g.y;
                acc[q].z += vv * g.z;
                acc[q].w += vv * g.w;
            }
        }
    }
    float4* o4 = (float4*)(out + (size_t)n * C);
#pragma unroll
    for (int q = 0; q < 10; ++q) o4[q] = acc[q];
}

// projB: P1[n] = x[n]@G1 (fp32, stride C) ; P2B[n] = bf16(x[n]@G2) (stride RP, 128B rows)
__global__ __launch_bounds__(256) void projB(const float* __restrict__ X,
                                             const float* __restrict__ G,
                                             float* __restrict__ P1,
                                             unsigned* __restrict__ P2B) {
    __shared__ __align__(16) float gs[2 * D * C];  // 41 KB -> 3 blocks/CU
    for (int i = threadIdx.x; i < 2 * D * C; i += 256) gs[i] = G[D * C + i];
    __syncthreads();

    int n = blockIdx.x * blockDim.x + threadIdx.x;
    if (n >= N) return;

    float4 a1[10], a2[10];
#pragma unroll
    for (int q = 0; q < 10; ++q) {
        a1[q] = make_float4(0.f, 0.f, 0.f, 0.f);
        a2[q] = make_float4(0.f, 0.f, 0.f, 0.f);
    }

    const float4* T4 = (const float4*)(X + (size_t)n * D);
    for (int dq = 0; dq < D / 4; ++dq) {
        float4 v = T4[dq];
#pragma unroll
        for (int j = 0; j < 4; ++j) {
            float vv = (j == 0 ? v.x : (j == 1 ? v.y : (j == 2 ? v.z : v.w)));
            const float4* g1 = (const float4*)(gs + (dq * 4 + j) * C);
            const float4* g2 = (const float4*)(gs + D * C + (dq * 4 + j) * C);
#pragma unroll
            for (int q = 0; q < 10; ++q) {
                float4 g = g1[q];
                a1[q].x += vv * g.x; a1[q].y += vv * g.y;
                a1[q].z += vv * g.z; a1[q].w += vv * g.w;
                float4 h = g2[q];
                a2[q].x += vv * h.x; a2[q].y += vv * h.y;
                a2[q].z += vv * h.z; a2[q].w += vv * h.w;
            }
        }
    }
    float4* p4 = (float4*)(P1 + (size_t)n * C);
#pragma unroll
    for (int q = 0; q < 10; ++q) p4[q] = a1[q];

    uint4* pb = (uint4*)(P2B + ((size_t)n << 5));  // 128B-aligned padded rows
#pragma unroll
    for (int q = 0; q < 5; ++q) {
        uint4 w;
        w.x = pack_bf2(a2[2 * q].x, a2[2 * q].y);
        w.y = pack_bf2(a2[2 * q].z, a2[2 * q].w);
        w.z = pack_bf2(a2[2 * q + 1].x, a2[2 * q + 1].y);
        w.w = pack_bf2(a2[2 * q + 1].z, a2[2 * q + 1].w);
        pb[q] = w;
    }
}

// gather SpMM on bf16-packed padded rows, fused rw-norm and add:
//   Y[n] = Add[n] + (sum_e w_e * Xg[src_e]) / max(sum_e w_e, 1e-12)
// one wave/node, lanes 0-31 even edges / 32-63 odd edges. The edge loop is
// batch-unrolled (16 edges = 8 per half per batch) with clamped indices and
// zeroed weights for the tail, so 8 gathers issue back-to-back per batch
// instead of one latency-exposed gather per runtime-bound iteration.
template <bool OUT_BF>
__global__ __launch_bounds__(256) void spmm40bf(const int* __restrict__ cur,
                                                const int2* __restrict__ csr,
                                                const unsigned* __restrict__ Xg,
                                                const float* __restrict__ Add,
                                                void* __restrict__ Yv) {
    int wid = (blockIdx.x * blockDim.x + threadIdx.x) >> 6;
    int lane = threadIdx.x & 63;
    if (wid >= N) return;
    int c = cur[wid];
    int2 p = make_int2(0, 0);
    if (lane < c) p = csr[((size_t)wid << 6) + lane];
    float myw = __int_as_float(p.y);
    float deg = myw;
#pragma unroll
    for (int off = 32; off > 0; off >>= 1) deg += __shfl_xor(deg, off);
    float rdeg = 1.f / fmaxf(deg, 1e-12f);

    int half = lane >> 5;
    int l2 = lane & 31;
    float2 acc = make_float2(0.f, 0.f);
    for (int j0 = 0; j0 < c; j0 += 16) {
        int cols[8];
        float ws8[8];
#pragma unroll
        for (int k = 0; k < 8; ++k) {
            int j = j0 + 2 * k + half;
            int js = min(j, c - 1);
            cols[k] = __shfl(p.x, js);
            float w = __shfl(myw, js);
            ws8[k] = (j < c) ? w : 0.f;
        }
        unsigned v8[8];
#pragma unroll
        for (int k = 0; k < 8; ++k)
            v8[k] = Xg[((size_t)cols[k] << 5) + l2];  // l2<32 stays inside padded row
#pragma unroll
        for (int k = 0; k < 8; ++k) {
            float2 v = unpack_bf2(v8[k]);
            acc.x = fmaf(ws8[k], v.x, acc.x);
            acc.y = fmaf(ws8[k], v.y, acc.y);
        }
    }
    acc.x += __shfl_xor(acc.x, 32);
    acc.y += __shfl_xor(acc.y, 32);

    if (lane < C2) {
        float2 ad = ((const float2*)Add)[(size_t)wid * C2 + lane];
        float ox = fmaf(acc.x, rdeg, ad.x);
        float oy = fmaf(acc.y, rdeg, ad.y);
        if (OUT_BF)
            ((unsigned*)Yv)[((size_t)wid << 5) + lane] = pack_bf2(ox, oy);
        else
            ((float2*)Yv)[(size_t)wid * C2 + lane] = make_float2(ox, oy);
    }
}

extern "C" void kernel_launch(void* const* d_in, const int* in_sizes, int n_in,
                              void* d_out, int out_size, void* d_ws, size_t ws_size,
                              hipStream_t stream) {
    const float* x = (const float*)d_in[0];
    const int* ei = (const int*)d_in[1];   // (2, E): src = ei, dst = ei + E
    const float* ew = (const float*)d_in[2];
    const float* W = (const float*)d_in[3];
    const float* b = (const float*)d_in[4];
    const float* Wd = (const float*)d_in[5];
    const float* bd = (const float*)d_in[6];
    float* out = (float*)d_out;

    const int* src = ei;
    const int* dst = ei + E;

    float* ws = (float*)d_ws;
    int* bcur = (int*)(ws + OFF_BCUR);
    int* cur = (int*)(ws + OFF_CUR);
    int2* csr = (int2*)(ws + OFF_CSR);
    int4* bbuf = (int4*)(ws + OFF_BBUF);
    float* P1 = ws + OFF_P1;
    unsigned* P2B = (unsigned*)(ws + OFF_P2B);
    unsigned* Rbf = (unsigned*)(ws + OFF_RBF);
    float* G = ws + OFF_G;
    float* bc = ws + OFF_BC;

    // zero bucket cursors only
    hipMemsetAsync((char*)d_ws + OFF_BCUR * sizeof(int), 0, 512 * sizeof(int), stream);

    prep_weights<<<(3 * D * C + C + 255) / 256, 256, 0, stream>>>(W, b, Wd, bd, G, bc);

    // two-level counting sort -> padded CSR
    bucket_scatter<<<(E + TPB * EPB - 1) / (TPB * EPB), TPB, 0, stream>>>(src, dst, ew, bcur, bbuf);
    csr_build<<<NB, 256, 0, stream>>>(bcur, bbuf, cur, csr);

    // out = x@G0 + bc ; P1 = x@G1 ; P2B = bf16(x@G2)  (P1/P2B overwrite bbuf — dead by now)
    projA<<<(N + 255) / 256, 256, 0, stream>>>(x, G, bc, out);
    projB<<<(N + 255) / 256, 256, 0, stream>>>(x, G, P1, P2B);

    // Rbf = bf16(P1 + A_hat @ P2)
    spmm40bf<true><<<((size_t)N * 64 + 255) / 256, 256, 0, stream>>>(cur, csr, P2B, P1, Rbf);
    // out += A_hat @ R
    spmm40bf<false><<<((size_t)N * 64 + 255) / 256, 256, 0, stream>>>(cur, csr, Rbf, out, out);
}

// Round 9
// 163.430 us; speedup vs baseline: 2.3577x; 1.3740x over previous
//
#include <hip/hip_runtime.h>

namespace {
constexpr int N = 100000;
constexpr int E = 1600000;
constexpr int D = 128;
constexpr int U = 64;
constexpr int C = 40;
constexpr int C2 = C / 2;   // 20 packed bf16x2 words per row
constexpr int RP = 32;      // padded row stride in u32 (128 B)
constexpr int SLOTS = 64;   // padded CSR slots per node; deg ~ Poisson(16), P(>64) ~ 1e-15
constexpr int NB = (N + 255) / 256;  // 391 buckets of 256 nodes
constexpr int CAP = 4608;   // bucket capacity
constexpr int EPB = 16;
constexpr int TPB = 256;
constexpr int GK = 136;     // padded Gbf/A row stride in bf16 (272 B: 2-way bank alias = free)

// workspace layout (element offsets; 4-byte units; keep 128B (32-elt) alignment)
constexpr size_t OFF_BCUR = 0;                               // 512 ints
constexpr size_t OFF_CUR = OFF_BCUR + 512;                   // N ints
constexpr size_t OFF_CSR = OFF_CUR + N;                      // 2*N*SLOTS ints
constexpr size_t OFF_BBUF = OFF_CSR + (size_t)2 * N * SLOTS; // NB*CAP*4 ints
// P1 (fp32, stride C) and P2B (bf16x2, stride RP) overlay BBUF (dead after csr_build)
constexpr size_t OFF_P1 = OFF_BBUF;                          // N*C floats
constexpr size_t OFF_P2B = OFF_P1 + (size_t)N * C + 32;      // N*RP u32
constexpr size_t BBUF_INTS = (size_t)NB * CAP * 4;
constexpr size_t PROJ_INTS = (size_t)N * C + 32 + (size_t)N * RP;
constexpr size_t REGION = BBUF_INTS > PROJ_INTS ? BBUF_INTS : PROJ_INTS;
constexpr size_t OFF_RBF = OFF_BBUF + REGION;                // N*RP u32
constexpr size_t OFF_GBF = OFF_RBF + (size_t)N * RP;         // 128*GK u16 = 8704 u32
constexpr size_t OFF_BC = OFF_GBF + 128 * GK / 2;            // C floats
} // namespace

// ---- bf16 pack/unpack (RNE) ----
__device__ inline unsigned f2bf(float x) {
    unsigned u = __float_as_uint(x);
    return (u + 0x7fffu + ((u >> 16) & 1u)) >> 16;
}
__device__ inline unsigned pack_bf2(float a, float b) { return f2bf(a) | (f2bf(b) << 16); }
__device__ inline float2 unpack_bf2(unsigned v) {
    return make_float2(__uint_as_float(v << 16), __uint_as_float(v & 0xffff0000u));
}

// ---- fold weights into one bf16 B^T matrix Gbf[n][k] (n=0..119 used, padded to 128):
//   n<40:  G0 = (W0-W2)@Wd ; n<80: G1 = -(W1@Wd) ; n<120: G2 = 2*(W2@Wd) ; else 0
// plus bc = b@Wd + bd (fp32)
__global__ void prep_weights(const float* __restrict__ W, const float* __restrict__ b,
                             const float* __restrict__ Wd, const float* __restrict__ bd,
                             unsigned short* __restrict__ Gbf, float* __restrict__ bc) {
    int t = blockIdx.x * blockDim.x + threadIdx.x;
    if (t < 128 * 128) {
        int n = t >> 7, k = t & 127;
        float s = 0.f;
        if (n < 40) {
            const float* W0 = W + (size_t)k * U;
            const float* W2 = W + (size_t)2 * D * U + (size_t)k * U;
            for (int u = 0; u < U; ++u) s += (W0[u] - W2[u]) * Wd[u * C + n];
        } else if (n < 80) {
            const float* W1 = W + (size_t)D * U + (size_t)k * U;
            for (int u = 0; u < U; ++u) s -= W1[u] * Wd[u * C + (n - 40)];
        } else if (n < 120) {
            const float* W2 = W + (size_t)2 * D * U + (size_t)k * U;
            for (int u = 0; u < U; ++u) s += 2.f * W2[u] * Wd[u * C + (n - 80)];
        }
        Gbf[n * GK + k] = (unsigned short)f2bf(s);
    } else if (t < 128 * 128 + C) {
        int c = t - 128 * 128;
        float s = bd[c];
        for (int u = 0; u < U; ++u) s += b[u] * Wd[u * C + c];
        bc[c] = s;
    }
}

// Pass C: two-level counting scatter into per-bucket contiguous regions.
__global__ __launch_bounds__(TPB) void bucket_scatter(const int* __restrict__ src,
                                                      const int* __restrict__ dst,
                                                      const float* __restrict__ ew,
                                                      int* __restrict__ bcur,
                                                      int4* __restrict__ bbuf) {
    __shared__ int hist[NB];
    __shared__ int base[NB];
    int t = threadIdx.x;
    for (int i = t; i < NB; i += TPB) hist[i] = 0;
    __syncthreads();

    size_t e0 = (size_t)blockIdx.x * (TPB * EPB);
    int ms[EPB], md[EPB], mw[EPB], mr[EPB];
#pragma unroll
    for (int k = 0; k < EPB; ++k) {
        size_t e = e0 + (size_t)k * TPB + t;
        if (e < E) {
            ms[k] = src[e];
            md[k] = dst[e];
            mw[k] = __float_as_int(ew[e]);
            mr[k] = atomicAdd(&hist[md[k] >> 8], 1);
        } else {
            md[k] = -1;
        }
    }
    __syncthreads();
    for (int i = t; i < NB; i += TPB) {
        int c = hist[i];
        base[i] = c ? atomicAdd(&bcur[i], c) : 0;
    }
    __syncthreads();
#pragma unroll
    for (int k = 0; k < EPB; ++k) {
        if (md[k] >= 0) {
            int bkt = md[k] >> 8;
            int slot = base[bkt] + mr[k];
            if (slot < CAP) bbuf[(size_t)bkt * CAP + slot] = make_int4(ms[k], mw[k], md[k], 0);
        }
    }
}

// Pass D: one block per bucket; LDS-only slotting.
__global__ __launch_bounds__(256) void csr_build(const int* __restrict__ bcur,
                                                 const int4* __restrict__ bbuf,
                                                 int* __restrict__ cur,
                                                 int2* __restrict__ csr) {
    __shared__ int lcur[256];
    int b = blockIdx.x;
    int t = threadIdx.x;
    lcur[t] = 0;
    __syncthreads();
    int cnt = min(bcur[b], CAP);
    for (int i = t; i < cnt; i += 256) {
        int4 r = bbuf[(size_t)b * CAP + i];
        int slot = atomicAdd(&lcur[r.z & 255], 1);
        if (slot < SLOTS) csr[((size_t)r.z << 6) + slot] = make_int2(r.x, r.y);
    }
    __syncthreads();
    int node = (b << 8) + t;
    if (node < N) cur[node] = min(lcur[t], SLOTS);
}

// proj_mfma: one 64-row tile per block, [64x128] @ [128x120] bf16 MFMA GEMM.
//   cols 0-39 -> out(+bc, fp32) ; 40-79 -> P1 (fp32) ; 80-119 -> P2B (bf16 u16)
// A staged bf16 [row][k] stride GK; B = Gbf [n][k] stride GK (B^T form, k-contiguous
// bf16x8 fragments; C/D: col=lane&15, row=(lane>>4)*4+reg  [m89-verified mapping]).
typedef __attribute__((ext_vector_type(8))) short bf16x8;
typedef __attribute__((ext_vector_type(4))) float f32x4;

__global__ __launch_bounds__(256) void proj_mfma(const float* __restrict__ X,
                                                 const unsigned* __restrict__ Gu,
                                                 const float* __restrict__ bc,
                                                 float* __restrict__ out,
                                                 float* __restrict__ P1,
                                                 unsigned short* __restrict__ P2B16) {
    __shared__ __align__(16) unsigned short a_s[64 * GK];   // 17.4 KB
    __shared__ __align__(16) unsigned short g_s[128 * GK];  // 34.8 KB
    __shared__ float bc_s[C];
    int t = threadIdx.x;
    int rb = blockIdx.x;

    // stage G (flat coalesced u32 copy)
    unsigned* gsu = (unsigned*)g_s;
    for (int i = t; i < 128 * GK / 2; i += 256) gsu[i] = Gu[i];
    if (t < C) bc_s[t] = bc[t];

    // stage A: 64 rows x 32 float4 (coalesced), convert to bf16
#pragma unroll
    for (int i = 0; i < 8; ++i) {
        int idx = i * 256 + t;
        int row = idx >> 5, kq = idx & 31;
        size_t grow = (size_t)rb * 64 + row;
        float4 v = (grow < N) ? ((const float4*)X)[grow * 32 + kq]
                              : make_float4(0.f, 0.f, 0.f, 0.f);
        unsigned* dstp = (unsigned*)(a_s + row * GK + kq * 4);
        dstp[0] = pack_bf2(v.x, v.y);
        dstp[1] = pack_bf2(v.z, v.w);
    }
    __syncthreads();

    int w = t >> 6, l = t & 63;
    int lr = l & 15, lh = l >> 4;

    bf16x8 afr[4];
#pragma unroll
    for (int ks = 0; ks < 4; ++ks)
        afr[ks] = *(const bf16x8*)(a_s + (w * 16 + lr) * GK + ks * 32 + lh * 8);

    f32x4 acc[8];
#pragma unroll
    for (int tt = 0; tt < 8; ++tt) {
        acc[tt] = (f32x4){0.f, 0.f, 0.f, 0.f};
#pragma unroll
        for (int ks = 0; ks < 4; ++ks) {
            bf16x8 bfr = *(const bf16x8*)(g_s + (tt * 16 + lr) * GK + ks * 32 + lh * 8);
            acc[tt] = __builtin_amdgcn_mfma_f32_16x16x32_bf16(afr[ks], bfr, acc[tt], 0, 0, 0);
        }
    }

    // epilogue: scatter columns to out / P1 / P2B
#pragma unroll
    for (int tt = 0; tt < 8; ++tt) {
        int gcol = tt * 16 + lr;
#pragma unroll
        for (int r = 0; r < 4; ++r) {
            size_t grow = (size_t)rb * 64 + w * 16 + lh * 4 + r;
            if (grow >= N) continue;
            float v = acc[tt][r];
            if (gcol < 40) {
                out[grow * C + gcol] = v + bc_s[gcol];
            } else if (gcol < 80) {
                P1[grow * C + (gcol - 40)] = v;
            } else if (gcol < 120) {
                P2B16[grow * 64 + (gcol - 80)] = (unsigned short)f2bf(v);
            }
        }
    }
}

// gather SpMM on bf16-packed padded rows, fused rw-norm and add:
//   Y[n] = Add[n] + (sum_e w_e * Xg[src_e]) / max(sum_e w_e, 1e-12)
// one wave/node, lanes 0-31 even edges / 32-63 odd edges; 16-edge batches with
// clamped indices + zeroed tail weights so 8 gathers issue back-to-back.
template <bool OUT_BF>
__global__ __launch_bounds__(256) void spmm40bf(const int* __restrict__ cur,
                                                const int2* __restrict__ csr,
                                                const unsigned* __restrict__ Xg,
                                                const float* __restrict__ Add,
                                                void* __restrict__ Yv) {
    int wid = (blockIdx.x * blockDim.x + threadIdx.x) >> 6;
    int lane = threadIdx.x & 63;
    if (wid >= N) return;
    int c = cur[wid];
    int2 p = make_int2(0, 0);
    if (lane < c) p = csr[((size_t)wid << 6) + lane];
    float myw = __int_as_float(p.y);
    float deg = myw;
#pragma unroll
    for (int off = 32; off > 0; off >>= 1) deg += __shfl_xor(deg, off);
    float rdeg = 1.f / fmaxf(deg, 1e-12f);

    int half = lane >> 5;
    int l2 = lane & 31;
    float2 acc = make_float2(0.f, 0.f);
    for (int j0 = 0; j0 < c; j0 += 16) {
        int cols[8];
        float ws8[8];
#pragma unroll
        for (int k = 0; k < 8; ++k) {
            int j = j0 + 2 * k + half;
            int js = min(j, c - 1);
            cols[k] = __shfl(p.x, js);
            float w = __shfl(myw, js);
            ws8[k] = (j < c) ? w : 0.f;
        }
        unsigned v8[8];
#pragma unroll
        for (int k = 0; k < 8; ++k)
            v8[k] = Xg[((size_t)cols[k] << 5) + l2];  // l2<32 stays inside padded row
#pragma unroll
        for (int k = 0; k < 8; ++k) {
            float2 v = unpack_bf2(v8[k]);
            acc.x = fmaf(ws8[k], v.x, acc.x);
            acc.y = fmaf(ws8[k], v.y, acc.y);
        }
    }
    acc.x += __shfl_xor(acc.x, 32);
    acc.y += __shfl_xor(acc.y, 32);

    if (lane < C2) {
        float2 ad = ((const float2*)Add)[(size_t)wid * C2 + lane];
        float ox = fmaf(acc.x, rdeg, ad.x);
        float oy = fmaf(acc.y, rdeg, ad.y);
        if (OUT_BF)
            ((unsigned*)Yv)[((size_t)wid << 5) + lane] = pack_bf2(ox, oy);
        else
            ((float2*)Yv)[(size_t)wid * C2 + lane] = make_float2(ox, oy);
    }
}

extern "C" void kernel_launch(void* const* d_in, const int* in_sizes, int n_in,
                              void* d_out, int out_size, void* d_ws, size_t ws_size,
                              hipStream_t stream) {
    const float* x = (const float*)d_in[0];
    const int* ei = (const int*)d_in[1];   // (2, E): src = ei, dst = ei + E
    const float* ew = (const float*)d_in[2];
    const float* W = (const float*)d_in[3];
    const float* b = (const float*)d_in[4];
    const float* Wd = (const float*)d_in[5];
    const float* bd = (const float*)d_in[6];
    float* out = (float*)d_out;

    const int* src = ei;
    const int* dst = ei + E;

    float* ws = (float*)d_ws;
    int* bcur = (int*)(ws + OFF_BCUR);
    int* cur = (int*)(ws + OFF_CUR);
    int2* csr = (int2*)(ws + OFF_CSR);
    int4* bbuf = (int4*)(ws + OFF_BBUF);
    float* P1 = ws + OFF_P1;
    unsigned* P2B = (unsigned*)(ws + OFF_P2B);
    unsigned* Rbf = (unsigned*)(ws + OFF_RBF);
    unsigned short* Gbf = (unsigned short*)(ws + OFF_GBF);
    float* bc = ws + OFF_BC;

    // zero bucket cursors only
    hipMemsetAsync((char*)d_ws + OFF_BCUR * sizeof(int), 0, 512 * sizeof(int), stream);

    prep_weights<<<(128 * 128 + C + 255) / 256, 256, 0, stream>>>(W, b, Wd, bd, Gbf, bc);

    // two-level counting sort -> padded CSR
    bucket_scatter<<<(E + TPB * EPB - 1) / (TPB * EPB), TPB, 0, stream>>>(src, dst, ew, bcur, bbuf);
    csr_build<<<NB, 256, 0, stream>>>(bcur, bbuf, cur, csr);

    // one MFMA GEMM: out = x@G0 + bc ; P1 = x@G1 ; P2B = bf16(x@G2)
    // (P1/P2B overwrite bbuf — dead by now)
    proj_mfma<<<(N + 63) / 64, 256, 0, stream>>>(x, (const unsigned*)Gbf, bc, out, P1,
                                                 (unsigned short*)P2B);

    // Rbf = bf16(P1 + A_hat @ P2)
    spmm40bf<true><<<((size_t)N * 64 + 255) / 256, 256, 0, stream>>>(cur, csr, P2B, P1, Rbf);
    // out += A_hat @ R
    spmm40bf<false><<<((size_t)N * 64 + 255) / 256, 256, 0, stream>>>(cur, csr, Rbf, out, out);
}

// Round 10
// 162.549 us; speedup vs baseline: 2.3705x; 1.0054x over previous
//
#include <hip/hip_runtime.h>

namespace {
constexpr int N = 100000;
constexpr int E = 1600000;
constexpr int D = 128;
constexpr int U = 64;
constexpr int C = 40;
constexpr int C2 = C / 2;   // 20 packed bf16x2 words per row
constexpr int RP = 32;      // padded row stride in u32 (128 B)
constexpr int SLOTS = 64;   // padded CSR slots per node; deg ~ Poisson(16), P(>64) ~ 1e-15
constexpr int NB = (N + 255) / 256;  // 391 buckets of 256 nodes
constexpr int CAP = 4608;   // bucket capacity
constexpr int EPB = 16;
constexpr int TPB = 256;
constexpr int GK = 136;     // padded Gbf/A row stride in bf16 (272 B: 2-way bank alias = free)

// workspace layout (element offsets; 4-byte units; keep 128B (32-elt) alignment)
constexpr size_t OFF_BCUR = 0;                               // 512 ints
constexpr size_t OFF_CUR = OFF_BCUR + 512;                   // N ints
constexpr size_t OFF_CSR = OFF_CUR + N;                      // 2*N*SLOTS ints
constexpr size_t OFF_BBUF = OFF_CSR + (size_t)2 * N * SLOTS; // NB*CAP*4 ints
// P1 (fp32, stride C) and P2B (bf16x2, stride RP) overlay BBUF (dead after csr_build)
constexpr size_t OFF_P1 = OFF_BBUF;                          // N*C floats
constexpr size_t OFF_P2B = OFF_P1 + (size_t)N * C + 32;      // N*RP u32
constexpr size_t BBUF_INTS = (size_t)NB * CAP * 4;
constexpr size_t PROJ_INTS = (size_t)N * C + 32 + (size_t)N * RP;
constexpr size_t REGION = BBUF_INTS > PROJ_INTS ? BBUF_INTS : PROJ_INTS;
constexpr size_t OFF_RBF = OFF_BBUF + REGION;                // N*RP u32
constexpr size_t OFF_GBF = OFF_RBF + (size_t)N * RP;         // 128*GK u16 = 8704 u32
constexpr size_t OFF_BC = OFF_GBF + 128 * GK / 2;            // C floats
} // namespace

// ---- bf16 pack/unpack (RNE) ----
__device__ inline unsigned f2bf(float x) {
    unsigned u = __float_as_uint(x);
    return (u + 0x7fffu + ((u >> 16) & 1u)) >> 16;
}
__device__ inline unsigned pack_bf2(float a, float b) { return f2bf(a) | (f2bf(b) << 16); }
__device__ inline float2 unpack_bf2(unsigned v) {
    return make_float2(__uint_as_float(v << 16), __uint_as_float(v & 0xffff0000u));
}

// ---- fold weights into one bf16 B^T matrix Gbf[n][k] (n=0..119 used, padded to 128):
//   n<40:  G0 = (W0-W2)@Wd ; n<80: G1 = -(W1@Wd) ; n<120: G2 = 2*(W2@Wd) ; else 0
// plus bc = b@Wd + bd (fp32)
__global__ void prep_weights(const float* __restrict__ W, const float* __restrict__ b,
                             const float* __restrict__ Wd, const float* __restrict__ bd,
                             unsigned short* __restrict__ Gbf, float* __restrict__ bc) {
    int t = blockIdx.x * blockDim.x + threadIdx.x;
    if (t < 128 * 128) {
        int n = t >> 7, k = t & 127;
        float s = 0.f;
        if (n < 40) {
            const float* W0 = W + (size_t)k * U;
            const float* W2 = W + (size_t)2 * D * U + (size_t)k * U;
            for (int u = 0; u < U; ++u) s += (W0[u] - W2[u]) * Wd[u * C + n];
        } else if (n < 80) {
            const float* W1 = W + (size_t)D * U + (size_t)k * U;
            for (int u = 0; u < U; ++u) s -= W1[u] * Wd[u * C + (n - 40)];
        } else if (n < 120) {
            const float* W2 = W + (size_t)2 * D * U + (size_t)k * U;
            for (int u = 0; u < U; ++u) s += 2.f * W2[u] * Wd[u * C + (n - 80)];
        }
        Gbf[n * GK + k] = (unsigned short)f2bf(s);
    } else if (t < 128 * 128 + C) {
        int c = t - 128 * 128;
        float s = bd[c];
        for (int u = 0; u < U; ++u) s += b[u] * Wd[u * C + c];
        bc[c] = s;
    }
}

// Pass C: two-level counting scatter into per-bucket contiguous regions.
__global__ __launch_bounds__(TPB) void bucket_scatter(const int* __restrict__ src,
                                                      const int* __restrict__ dst,
                                                      const float* __restrict__ ew,
                                                      int* __restrict__ bcur,
                                                      int4* __restrict__ bbuf) {
    __shared__ int hist[NB];
    __shared__ int base[NB];
    int t = threadIdx.x;
    for (int i = t; i < NB; i += TPB) hist[i] = 0;
    __syncthreads();

    size_t e0 = (size_t)blockIdx.x * (TPB * EPB);
    int ms[EPB], md[EPB], mw[EPB], mr[EPB];
#pragma unroll
    for (int k = 0; k < EPB; ++k) {
        size_t e = e0 + (size_t)k * TPB + t;
        if (e < E) {
            ms[k] = src[e];
            md[k] = dst[e];
            mw[k] = __float_as_int(ew[e]);
            mr[k] = atomicAdd(&hist[md[k] >> 8], 1);
        } else {
            md[k] = -1;
        }
    }
    __syncthreads();
    for (int i = t; i < NB; i += TPB) {
        int c = hist[i];
        base[i] = c ? atomicAdd(&bcur[i], c) : 0;
    }
    __syncthreads();
#pragma unroll
    for (int k = 0; k < EPB; ++k) {
        if (md[k] >= 0) {
            int bkt = md[k] >> 8;
            int slot = base[bkt] + mr[k];
            if (slot < CAP) bbuf[(size_t)bkt * CAP + slot] = make_int4(ms[k], mw[k], md[k], 0);
        }
    }
}

// Pass D: one block per bucket; LDS-only slotting. Zero-fills each node's CSR
// padding to the next multiple of 8 so the SpMM edge loop needs no tail masking.
__global__ __launch_bounds__(256) void csr_build(const int* __restrict__ bcur,
                                                 const int4* __restrict__ bbuf,
                                                 int* __restrict__ cur,
                                                 int2* __restrict__ csr) {
    __shared__ int lcur[256];
    int b = blockIdx.x;
    int t = threadIdx.x;
    lcur[t] = 0;
    __syncthreads();
    int cnt = min(bcur[b], CAP);
    for (int i = t; i < cnt; i += 256) {
        int4 r = bbuf[(size_t)b * CAP + i];
        int slot = atomicAdd(&lcur[r.z & 255], 1);
        if (slot < SLOTS) csr[((size_t)r.z << 6) + slot] = make_int2(r.x, r.y);
    }
    __syncthreads();
    int node = (b << 8) + t;
    if (node < N) {
        int c = min(lcur[t], SLOTS);
        cur[node] = c;
        int padded = min((c + 7) & ~7, SLOTS);
        for (int s = c; s < padded; ++s)
            csr[((size_t)node << 6) + s] = make_int2(0, 0);
    }
}

// proj_mfma: one 64-row tile per block, [64x128] @ [128x120] bf16 MFMA GEMM.
//   cols 0-39 -> out(+bc, fp32) ; 40-79 -> P1 (fp32) ; 80-119 -> P2B (bf16 u16)
typedef __attribute__((ext_vector_type(8))) short bf16x8;
typedef __attribute__((ext_vector_type(4))) float f32x4;

__global__ __launch_bounds__(256) void proj_mfma(const float* __restrict__ X,
                                                 const unsigned* __restrict__ Gu,
                                                 const float* __restrict__ bc,
                                                 float* __restrict__ out,
                                                 float* __restrict__ P1,
                                                 unsigned short* __restrict__ P2B16) {
    __shared__ __align__(16) unsigned short a_s[64 * GK];   // 17.4 KB
    __shared__ __align__(16) unsigned short g_s[128 * GK];  // 34.8 KB
    __shared__ float bc_s[C];
    int t = threadIdx.x;
    int rb = blockIdx.x;

    // stage G (flat coalesced u32 copy)
    unsigned* gsu = (unsigned*)g_s;
    for (int i = t; i < 128 * GK / 2; i += 256) gsu[i] = Gu[i];
    if (t < C) bc_s[t] = bc[t];

    // stage A: 64 rows x 32 float4 (coalesced), convert to bf16
#pragma unroll
    for (int i = 0; i < 8; ++i) {
        int idx = i * 256 + t;
        int row = idx >> 5, kq = idx & 31;
        size_t grow = (size_t)rb * 64 + row;
        float4 v = (grow < N) ? ((const float4*)X)[grow * 32 + kq]
                              : make_float4(0.f, 0.f, 0.f, 0.f);
        unsigned* dstp = (unsigned*)(a_s + row * GK + kq * 4);
        dstp[0] = pack_bf2(v.x, v.y);
        dstp[1] = pack_bf2(v.z, v.w);
    }
    __syncthreads();

    int w = t >> 6, l = t & 63;
    int lr = l & 15, lh = l >> 4;

    bf16x8 afr[4];
#pragma unroll
    for (int ks = 0; ks < 4; ++ks)
        afr[ks] = *(const bf16x8*)(a_s + (w * 16 + lr) * GK + ks * 32 + lh * 8);

    f32x4 acc[8];
#pragma unroll
    for (int tt = 0; tt < 8; ++tt) {
        acc[tt] = (f32x4){0.f, 0.f, 0.f, 0.f};
#pragma unroll
        for (int ks = 0; ks < 4; ++ks) {
            bf16x8 bfr = *(const bf16x8*)(g_s + (tt * 16 + lr) * GK + ks * 32 + lh * 8);
            acc[tt] = __builtin_amdgcn_mfma_f32_16x16x32_bf16(afr[ks], bfr, acc[tt], 0, 0, 0);
        }
    }

    // epilogue: scatter columns to out / P1 / P2B
#pragma unroll
    for (int tt = 0; tt < 8; ++tt) {
        int gcol = tt * 16 + lr;
#pragma unroll
        for (int r = 0; r < 4; ++r) {
            size_t grow = (size_t)rb * 64 + w * 16 + lh * 4 + r;
            if (grow >= N) continue;
            float v = acc[tt][r];
            if (gcol < 40) {
                out[grow * C + gcol] = v + bc_s[gcol];
            } else if (gcol < 80) {
                P1[grow * C + (gcol - 40)] = v;
            } else if (gcol < 120) {
                P2B16[grow * 64 + (gcol - 80)] = (unsigned short)f2bf(v);
            }
        }
    }
}

// gather SpMM v3: scalar-unit metadata, uniform edge loop, 32-bit addressing.
//   Y[n] = Add[n] + (sum_e w_e * Xg[src_e]) / max(sum_e w_e, 1e-12)
// One wave per node. CSR row address is wave-uniform (readfirstlane) -> the
// metadata loads become s_load into SGPRs (free broadcast to VALU operands).
// Half-split: per 8-edge batch, lanes 0-31 handle edges j0..j0+3, lanes 32-63
// handle j0+4..j0+7 (one cndmask pair/edge); combined via shfl_xor(32).
// CSR rows are zero-padded to a multiple of 8, so the loop has no tail masking.
template <bool OUT_BF>
__global__ __launch_bounds__(256) void spmm40v3(const int* __restrict__ cur,
                                                const int2* __restrict__ csr,
                                                const unsigned* __restrict__ Xg,
                                                const float* __restrict__ Add,
                                                void* __restrict__ Yv) {
    int wid = (blockIdx.x * blockDim.x + threadIdx.x) >> 6;
    if (wid >= N) return;
    int uw = __builtin_amdgcn_readfirstlane(wid);
    int c = cur[uw];                       // uniform -> s_load
    const int2* __restrict__ row = csr + ((size_t)uw << 6);
    int lane = threadIdx.x & 63;
    bool hi = lane >= 32;
    unsigned voff = (unsigned)(lane & 31); // word index within padded 32-word row

    float2 acc = make_float2(0.f, 0.f);
    float deg = 0.f;
    for (int j0 = 0; j0 < c; j0 += 8) {
        unsigned va[4];
        float wa[4];
#pragma unroll
        for (int k = 0; k < 4; ++k) {
            int2 a = row[j0 + k];          // uniform -> s_load_dwordx2
            int2 b = row[j0 + 4 + k];
            int col = hi ? b.x : a.x;      // 1 cndmask
            wa[k] = __int_as_float(hi ? b.y : a.y);
            va[k] = Xg[((unsigned)col << 5) + voff];  // SGPR base + 32-bit voffset
        }
#pragma unroll
        for (int k = 0; k < 4; ++k) {
            float2 v = unpack_bf2(va[k]);
            acc.x = fmaf(wa[k], v.x, acc.x);
            acc.y = fmaf(wa[k], v.y, acc.y);
            deg += wa[k];
        }
    }
    acc.x += __shfl_xor(acc.x, 32);
    acc.y += __shfl_xor(acc.y, 32);
    deg += __shfl_xor(deg, 32);
    float rdeg = 1.f / fmaxf(deg, 1e-12f);

    if (lane < C2) {
        float2 ad = ((const float2*)Add)[(size_t)wid * C2 + lane];
        float ox = fmaf(acc.x, rdeg, ad.x);
        float oy = fmaf(acc.y, rdeg, ad.y);
        if (OUT_BF)
            ((unsigned*)Yv)[((size_t)wid << 5) + lane] = pack_bf2(ox, oy);
        else
            ((float2*)Yv)[(size_t)wid * C2 + lane] = make_float2(ox, oy);
    }
}

extern "C" void kernel_launch(void* const* d_in, const int* in_sizes, int n_in,
                              void* d_out, int out_size, void* d_ws, size_t ws_size,
                              hipStream_t stream) {
    const float* x = (const float*)d_in[0];
    const int* ei = (const int*)d_in[1];   // (2, E): src = ei, dst = ei + E
    const float* ew = (const float*)d_in[2];
    const float* W = (const float*)d_in[3];
    const float* b = (const float*)d_in[4];
    const float* Wd = (const float*)d_in[5];
    const float* bd = (const float*)d_in[6];
    float* out = (float*)d_out;

    const int* src = ei;
    const int* dst = ei + E;

    float* ws = (float*)d_ws;
    int* bcur = (int*)(ws + OFF_BCUR);
    int* cur = (int*)(ws + OFF_CUR);
    int2* csr = (int2*)(ws + OFF_CSR);
    int4* bbuf = (int4*)(ws + OFF_BBUF);
    float* P1 = ws + OFF_P1;
    unsigned* P2B = (unsigned*)(ws + OFF_P2B);
    unsigned* Rbf = (unsigned*)(ws + OFF_RBF);
    unsigned short* Gbf = (unsigned short*)(ws + OFF_GBF);
    float* bc = ws + OFF_BC;

    // zero bucket cursors only
    hipMemsetAsync((char*)d_ws + OFF_BCUR * sizeof(int), 0, 512 * sizeof(int), stream);

    prep_weights<<<(128 * 128 + C + 255) / 256, 256, 0, stream>>>(W, b, Wd, bd, Gbf, bc);

    // two-level counting sort -> padded CSR (zero-padded to multiple of 8)
    bucket_scatter<<<(E + TPB * EPB - 1) / (TPB * EPB), TPB, 0, stream>>>(src, dst, ew, bcur, bbuf);
    csr_build<<<NB, 256, 0, stream>>>(bcur, bbuf, cur, csr);

    // one MFMA GEMM: out = x@G0 + bc ; P1 = x@G1 ; P2B = bf16(x@G2)
    proj_mfma<<<(N + 63) / 64, 256, 0, stream>>>(x, (const unsigned*)Gbf, bc, out, P1,
                                                 (unsigned short*)P2B);

    // Rbf = bf16(P1 + A_hat @ P2)
    spmm40v3<true><<<((size_t)N * 64 + 255) / 256, 256, 0, stream>>>(cur, csr, P2B, P1, Rbf);
    // out += A_hat @ R
    spmm40v3<false><<<((size_t)N * 64 + 255) / 256, 256, 0, stream>>>(cur, csr, Rbf, out, out);
}

// Round 11
// 150.184 us; speedup vs baseline: 2.5657x; 1.0823x over previous
//
#include <hip/hip_runtime.h>

namespace {
constexpr int N = 100000;
constexpr int E = 1600000;
constexpr int D = 128;
constexpr int U = 64;
constexpr int C = 40;
constexpr int C2 = C / 2;   // 20 packed bf16x2 words per row
constexpr int RP = 32;      // padded row stride in u32 (128 B)
constexpr int SLOTS = 64;   // padded CSR slots per node; deg ~ Poisson(16), P(>64) ~ 1e-15
constexpr int NB = (N + 255) / 256;  // 391 buckets of 256 nodes
constexpr int CAP = 4608;   // bucket capacity
constexpr int EPB = 16;
constexpr int TPB = 256;
constexpr int GK = 136;     // padded Gbf/A row stride in bf16 (272 B: 2-way bank alias = free)

// workspace layout (element offsets; 4-byte units; keep 128B (32-elt) alignment)
constexpr size_t OFF_BCUR = 0;                               // 512 ints
constexpr size_t OFF_META = OFF_BCUR + 512;                  // 2*N ints: {cnt, rdeg_bits}
constexpr size_t OFF_CSR = OFF_META + (size_t)2 * N;         // 2*N*SLOTS ints
constexpr size_t OFF_BBUF = OFF_CSR + (size_t)2 * N * SLOTS; // NB*CAP*4 ints
// P1 (fp32, stride C) and P2B (bf16x2, stride RP) overlay BBUF (dead after csr_build)
constexpr size_t OFF_P1 = OFF_BBUF;                          // N*C floats
constexpr size_t OFF_P2B = OFF_P1 + (size_t)N * C + 32;      // N*RP u32
constexpr size_t BBUF_INTS = (size_t)NB * CAP * 4;
constexpr size_t PROJ_INTS = (size_t)N * C + 32 + (size_t)N * RP;
constexpr size_t REGION = BBUF_INTS > PROJ_INTS ? BBUF_INTS : PROJ_INTS;
constexpr size_t OFF_RBF = OFF_BBUF + REGION;                // N*RP u32
constexpr size_t OFF_GBF = OFF_RBF + (size_t)N * RP;         // 128*GK u16 = 8704 u32
constexpr size_t OFF_BC = OFF_GBF + 128 * GK / 2;            // C floats
} // namespace

// ---- bf16 pack/unpack (RNE) ----
__device__ inline unsigned f2bf(float x) {
    unsigned u = __float_as_uint(x);
    return (u + 0x7fffu + ((u >> 16) & 1u)) >> 16;
}
__device__ inline unsigned pack_bf2(float a, float b) { return f2bf(a) | (f2bf(b) << 16); }
__device__ inline float2 unpack_bf2(unsigned v) {
    return make_float2(__uint_as_float(v << 16), __uint_as_float(v & 0xffff0000u));
}

// ---- fold weights into one bf16 B^T matrix Gbf[n][k] (n=0..119 used, padded to 128):
//   n<40:  G0 = (W0-W2)@Wd ; n<80: G1 = -(W1@Wd) ; n<120: G2 = 2*(W2@Wd) ; else 0
// plus bc = b@Wd + bd (fp32)
__global__ void prep_weights(const float* __restrict__ W, const float* __restrict__ b,
                             const float* __restrict__ Wd, const float* __restrict__ bd,
                             unsigned short* __restrict__ Gbf, float* __restrict__ bc) {
    int t = blockIdx.x * blockDim.x + threadIdx.x;
    if (t < 128 * 128) {
        int n = t >> 7, k = t & 127;
        float s = 0.f;
        if (n < 40) {
            const float* W0 = W + (size_t)k * U;
            const float* W2 = W + (size_t)2 * D * U + (size_t)k * U;
            for (int u = 0; u < U; ++u) s += (W0[u] - W2[u]) * Wd[u * C + n];
        } else if (n < 80) {
            const float* W1 = W + (size_t)D * U + (size_t)k * U;
            for (int u = 0; u < U; ++u) s -= W1[u] * Wd[u * C + (n - 40)];
        } else if (n < 120) {
            const float* W2 = W + (size_t)2 * D * U + (size_t)k * U;
            for (int u = 0; u < U; ++u) s += 2.f * W2[u] * Wd[u * C + (n - 80)];
        }
        Gbf[n * GK + k] = (unsigned short)f2bf(s);
    } else if (t < 128 * 128 + C) {
        int c = t - 128 * 128;
        float s = bd[c];
        for (int u = 0; u < U; ++u) s += b[u] * Wd[u * C + c];
        bc[c] = s;
    }
}

// Pass C: two-level counting scatter into per-bucket contiguous regions.
__global__ __launch_bounds__(TPB) void bucket_scatter(const int* __restrict__ src,
                                                      const int* __restrict__ dst,
                                                      const float* __restrict__ ew,
                                                      int* __restrict__ bcur,
                                                      int4* __restrict__ bbuf) {
    __shared__ int hist[NB];
    __shared__ int base[NB];
    int t = threadIdx.x;
    for (int i = t; i < NB; i += TPB) hist[i] = 0;
    __syncthreads();

    size_t e0 = (size_t)blockIdx.x * (TPB * EPB);
    int ms[EPB], md[EPB], mw[EPB], mr[EPB];
#pragma unroll
    for (int k = 0; k < EPB; ++k) {
        size_t e = e0 + (size_t)k * TPB + t;
        if (e < E) {
            ms[k] = src[e];
            md[k] = dst[e];
            mw[k] = __float_as_int(ew[e]);
            mr[k] = atomicAdd(&hist[md[k] >> 8], 1);
        } else {
            md[k] = -1;
        }
    }
    __syncthreads();
    for (int i = t; i < NB; i += TPB) {
        int c = hist[i];
        base[i] = c ? atomicAdd(&bcur[i], c) : 0;
    }
    __syncthreads();
#pragma unroll
    for (int k = 0; k < EPB; ++k) {
        if (md[k] >= 0) {
            int bkt = md[k] >> 8;
            int slot = base[bkt] + mr[k];
            if (slot < CAP) bbuf[(size_t)bkt * CAP + slot] = make_int4(ms[k], mw[k], md[k], 0);
        }
    }
}

// Pass D: one block per bucket; LDS-only slotting + weighted-degree accumulation.
// Writes meta[n] = {cnt, 1/max(deg,1e-12)} and zero-pads CSR rows to a multiple
// of 16 so the SpMM edge loop has no tail masking.
__global__ __launch_bounds__(256) void csr_build(const int* __restrict__ bcur,
                                                 const int4* __restrict__ bbuf,
                                                 int2* __restrict__ meta,
                                                 int2* __restrict__ csr) {
    __shared__ int lcur[256];
    __shared__ float lw[256];
    int b = blockIdx.x;
    int t = threadIdx.x;
    lcur[t] = 0;
    lw[t] = 0.f;
    __syncthreads();
    int cnt = min(bcur[b], CAP);
    for (int i = t; i < cnt; i += 256) {
        int4 r = bbuf[(size_t)b * CAP + i];
        int idx = r.z & 255;
        int slot = atomicAdd(&lcur[idx], 1);
        atomicAdd(&lw[idx], __int_as_float(r.y));  // full weighted degree (matches ref)
        if (slot < SLOTS) csr[((size_t)r.z << 6) + slot] = make_int2(r.x, r.y);
    }
    __syncthreads();
    int node = (b << 8) + t;
    if (node < N) {
        int c = min(lcur[t], SLOTS);
        float rdeg = 1.f / fmaxf(lw[t], 1e-12f);
        meta[node] = make_int2(c, __float_as_int(rdeg));
        int padded = min((c + 15) & ~15, SLOTS);
        for (int s = c; s < padded; ++s)
            csr[((size_t)node << 6) + s] = make_int2(0, 0);
    }
}

// proj_mfma: one 64-row tile per block, [64x128] @ [128x120] bf16 MFMA GEMM.
//   cols 0-39 -> out(+bc, fp32) ; 40-79 -> P1 (fp32) ; 80-119 -> P2B (bf16 u16)
typedef __attribute__((ext_vector_type(8))) short bf16x8;
typedef __attribute__((ext_vector_type(4))) float f32x4;

__global__ __launch_bounds__(256) void proj_mfma(const float* __restrict__ X,
                                                 const unsigned* __restrict__ Gu,
                                                 const float* __restrict__ bc,
                                                 float* __restrict__ out,
                                                 float* __restrict__ P1,
                                                 unsigned short* __restrict__ P2B16) {
    __shared__ __align__(16) unsigned short a_s[64 * GK];   // 17.4 KB
    __shared__ __align__(16) unsigned short g_s[128 * GK];  // 34.8 KB
    __shared__ float bc_s[C];
    int t = threadIdx.x;
    int rb = blockIdx.x;

    // stage G (flat coalesced u32 copy)
    unsigned* gsu = (unsigned*)g_s;
    for (int i = t; i < 128 * GK / 2; i += 256) gsu[i] = Gu[i];
    if (t < C) bc_s[t] = bc[t];

    // stage A: 64 rows x 32 float4 (coalesced), convert to bf16
#pragma unroll
    for (int i = 0; i < 8; ++i) {
        int idx = i * 256 + t;
        int row = idx >> 5, kq = idx & 31;
        size_t grow = (size_t)rb * 64 + row;
        float4 v = (grow < N) ? ((const float4*)X)[grow * 32 + kq]
                              : make_float4(0.f, 0.f, 0.f, 0.f);
        unsigned* dstp = (unsigned*)(a_s + row * GK + kq * 4);
        dstp[0] = pack_bf2(v.x, v.y);
        dstp[1] = pack_bf2(v.z, v.w);
    }
    __syncthreads();

    int w = t >> 6, l = t & 63;
    int lr = l & 15, lh = l >> 4;

    bf16x8 afr[4];
#pragma unroll
    for (int ks = 0; ks < 4; ++ks)
        afr[ks] = *(const bf16x8*)(a_s + (w * 16 + lr) * GK + ks * 32 + lh * 8);

    f32x4 acc[8];
#pragma unroll
    for (int tt = 0; tt < 8; ++tt) {
        acc[tt] = (f32x4){0.f, 0.f, 0.f, 0.f};
#pragma unroll
        for (int ks = 0; ks < 4; ++ks) {
            bf16x8 bfr = *(const bf16x8*)(g_s + (tt * 16 + lr) * GK + ks * 32 + lh * 8);
            acc[tt] = __builtin_amdgcn_mfma_f32_16x16x32_bf16(afr[ks], bfr, acc[tt], 0, 0, 0);
        }
    }

    // epilogue: scatter columns to out / P1 / P2B
#pragma unroll
    for (int tt = 0; tt < 8; ++tt) {
        int gcol = tt * 16 + lr;
#pragma unroll
        for (int r = 0; r < 4; ++r) {
            size_t grow = (size_t)rb * 64 + w * 16 + lh * 4 + r;
            if (grow >= N) continue;
            float v = acc[tt][r];
            if (gcol < 40) {
                out[grow * C + gcol] = v + bc_s[gcol];
            } else if (gcol < 80) {
                P1[grow * C + (gcol - 40)] = v;
            } else if (gcol < 120) {
                P2B16[grow * 64 + (gcol - 80)] = (unsigned short)f2bf(v);
            }
        }
    }
}

// gather SpMM v4: scalar metadata + precomputed rdeg + 16-edge batches.
//   Y[n] = Add[n] + rdeg * sum_e w_e * Xg[src_e]
// One wave/node. CSR rows zero-padded to multiple of 16 -> no tail masking.
// Lanes 0-31 handle edges j0..j0+7, lanes 32-63 handle j0+8..j0+15: 8
// independent gathers in flight per iteration; deg<=16 nodes need ONE iteration.
// OUT_BF writes the full 128B padded row (zeros in pad) -> no partial-line RMW.
template <bool OUT_BF>
__global__ __launch_bounds__(256) void spmm40v4(const int2* __restrict__ meta,
                                                const int2* __restrict__ csr,
                                                const unsigned* __restrict__ Xg,
                                                const float* __restrict__ Add,
                                                void* __restrict__ Yv) {
    int wid = (blockIdx.x * blockDim.x + threadIdx.x) >> 6;
    if (wid >= N) return;
    int uw = __builtin_amdgcn_readfirstlane(wid);
    int2 m = meta[uw];                     // uniform -> s_load_dwordx2
    int c = m.x;
    float rdeg = __int_as_float(m.y);
    const int2* __restrict__ row = csr + ((size_t)uw << 6);
    int lane = threadIdx.x & 63;
    bool hi = lane >= 32;
    unsigned voff = (unsigned)(lane & 31); // word index within padded 32-word row

    // preload Add early (independent of the gather chain)
    float2 ad = make_float2(0.f, 0.f);
    if (lane < C2) ad = ((const float2*)Add)[(size_t)wid * C2 + lane];

    float2 acc = make_float2(0.f, 0.f);
    for (int j0 = 0; j0 < c; j0 += 16) {
        unsigned va[8];
        float wa[8];
#pragma unroll
        for (int k = 0; k < 8; ++k) {
            int2 a = row[j0 + k];          // uniform -> s_load
            int2 b = row[j0 + 8 + k];
            int col = hi ? b.x : a.x;
            wa[k] = __int_as_float(hi ? b.y : a.y);
            va[k] = Xg[((unsigned)col << 5) + voff];  // SGPR base + 32-bit voffset
        }
#pragma unroll
        for (int k = 0; k < 8; ++k) {
            float2 v = unpack_bf2(va[k]);
            acc.x = fmaf(wa[k], v.x, acc.x);
            acc.y = fmaf(wa[k], v.y, acc.y);
        }
    }
    acc.x += __shfl_xor(acc.x, 32);
    acc.y += __shfl_xor(acc.y, 32);

    if (OUT_BF) {
        if (lane < 32) {
            unsigned o = 0u;
            if (lane < C2)
                o = pack_bf2(fmaf(acc.x, rdeg, ad.x), fmaf(acc.y, rdeg, ad.y));
            ((unsigned*)Yv)[((size_t)wid << 5) + lane] = o;  // full 128B row, no RMW
        }
    } else {
        if (lane < C2) {
            ((float2*)Yv)[(size_t)wid * C2 + lane] =
                make_float2(fmaf(acc.x, rdeg, ad.x), fmaf(acc.y, rdeg, ad.y));
        }
    }
}

extern "C" void kernel_launch(void* const* d_in, const int* in_sizes, int n_in,
                              void* d_out, int out_size, void* d_ws, size_t ws_size,
                              hipStream_t stream) {
    const float* x = (const float*)d_in[0];
    const int* ei = (const int*)d_in[1];   // (2, E): src = ei, dst = ei + E
    const float* ew = (const float*)d_in[2];
    const float* W = (const float*)d_in[3];
    const float* b = (const float*)d_in[4];
    const float* Wd = (const float*)d_in[5];
    const float* bd = (const float*)d_in[6];
    float* out = (float*)d_out;

    const int* src = ei;
    const int* dst = ei + E;

    float* ws = (float*)d_ws;
    int* bcur = (int*)(ws + OFF_BCUR);
    int2* meta = (int2*)(ws + OFF_META);
    int2* csr = (int2*)(ws + OFF_CSR);
    int4* bbuf = (int4*)(ws + OFF_BBUF);
    float* P1 = ws + OFF_P1;
    unsigned* P2B = (unsigned*)(ws + OFF_P2B);
    unsigned* Rbf = (unsigned*)(ws + OFF_RBF);
    unsigned short* Gbf = (unsigned short*)(ws + OFF_GBF);
    float* bc = ws + OFF_BC;

    // zero bucket cursors only
    hipMemsetAsync((char*)d_ws + OFF_BCUR * sizeof(int), 0, 512 * sizeof(int), stream);

    prep_weights<<<(128 * 128 + C + 255) / 256, 256, 0, stream>>>(W, b, Wd, bd, Gbf, bc);

    // two-level counting sort -> padded CSR (zero-padded to multiple of 16) + meta
    bucket_scatter<<<(E + TPB * EPB - 1) / (TPB * EPB), TPB, 0, stream>>>(src, dst, ew, bcur, bbuf);
    csr_build<<<NB, 256, 0, stream>>>(bcur, bbuf, meta, csr);

    // one MFMA GEMM: out = x@G0 + bc ; P1 = x@G1 ; P2B = bf16(x@G2)
    proj_mfma<<<(N + 63) / 64, 256, 0, stream>>>(x, (const unsigned*)Gbf, bc, out, P1,
                                                 (unsigned short*)P2B);

    // Rbf = bf16(P1 + A_hat @ P2)
    spmm40v4<true><<<((size_t)N * 64 + 255) / 256, 256, 0, stream>>>(meta, csr, P2B, P1, Rbf);
    // out += A_hat @ R
    spmm40v4<false><<<((size_t)N * 64 + 255) / 256, 256, 0, stream>>>(meta, csr, Rbf, out, out);
}

// Round 12
// 131.116 us; speedup vs baseline: 2.9388x; 1.1454x over previous
//
#include <hip/hip_runtime.h>

namespace {
constexpr int N = 100000;
constexpr int E = 1600000;
constexpr int D = 128;
constexpr int U = 64;
constexpr int C = 40;
constexpr int C2 = C / 2;   // 20 packed bf16x2 words per row
constexpr int RP = 32;      // padded row stride in u32 (128 B)
constexpr int SLOTS = 64;   // padded CSR slots per node; deg ~ Poisson(16), P(>64) ~ 1e-15
constexpr int NB = (N + 255) / 256;  // 391 buckets of 256 nodes
constexpr int CAP = 4608;   // bucket capacity
constexpr int EPB = 16;
constexpr int TPB = 256;
constexpr int GK = 136;     // padded Gbf/A row stride in bf16 (272 B: 2-way bank alias = free)
constexpr int PROJ_BLOCKS = (N + 63) / 64;  // 1563

// workspace layout (element offsets; 4-byte units; keep 128B (32-elt) alignment)
constexpr size_t OFF_BCUR = 0;                               // 512 ints
constexpr size_t OFF_META = OFF_BCUR + 512;                  // 2*N ints: {cnt, rdeg_bits}
constexpr size_t OFF_CSR = OFF_META + (size_t)2 * N;         // 2*N*SLOTS ints
constexpr size_t OFF_BBUF = OFF_CSR + (size_t)2 * N * SLOTS; // NB*CAP*2 ints (packed int2)
// P1 (fp32, stride C) and P2B (bf16x2, stride RP) overlay BBUF (dead after csr phase;
// the fused kernel's proj blocks only write P1/P2B for rows — BUT csr blocks read bbuf
// concurrently! So P1/P2B must NOT overlay bbuf anymore. Give them their own region.
constexpr size_t BBUF_INTS = (size_t)NB * CAP * 2;
constexpr size_t OFF_P1 = OFF_BBUF + BBUF_INTS;              // N*C floats
constexpr size_t OFF_P2B = OFF_P1 + (size_t)N * C + 32;      // N*RP u32
constexpr size_t OFF_RBF = OFF_P2B + (size_t)N * RP;         // N*RP u32
constexpr size_t OFF_GBF = OFF_RBF + (size_t)N * RP;         // 128*GK u16 = 8704 u32
constexpr size_t OFF_BC = OFF_GBF + 128 * GK / 2;            // C floats
// total ~ 200K + 12.8M + 3.6M + 4M + 3.2M + 3.2M + 8.7K + 40 ints ~= 107 MB

constexpr int SMEM_PROJ = 64 * GK * 2 + 128 * GK * 2 + ((C * 4 + 15) & ~15);  // 52.4 KB
} // namespace

// ---- bf16 pack/unpack (RNE) ----
__device__ inline unsigned f2bf(float x) {
    unsigned u = __float_as_uint(x);
    return (u + 0x7fffu + ((u >> 16) & 1u)) >> 16;
}
__device__ inline unsigned pack_bf2(float a, float b) { return f2bf(a) | (f2bf(b) << 16); }
__device__ inline float2 unpack_bf2(unsigned v) {
    return make_float2(__uint_as_float(v << 16), __uint_as_float(v & 0xffff0000u));
}

typedef __attribute__((ext_vector_type(8))) short bf16x8;
typedef __attribute__((ext_vector_type(4))) float f32x4;

// ---- fold weights into one bf16 B^T matrix Gbf[n][k] (n=0..119 used, padded to 128):
//   n<40:  G0 = (W0-W2)@Wd ; n<80: G1 = -(W1@Wd) ; n<120: G2 = 2*(W2@Wd) ; else 0
// plus bc = b@Wd + bd (fp32). Block 0 also zeroes the bucket cursors (replaces
// the pathologically slow 2KB hipMemsetAsync fill dispatch).
__global__ void prep_weights(const float* __restrict__ W, const float* __restrict__ b,
                             const float* __restrict__ Wd, const float* __restrict__ bd,
                             unsigned short* __restrict__ Gbf, float* __restrict__ bc,
                             int* __restrict__ bcur) {
    if (blockIdx.x == 0) {
        for (int i = threadIdx.x; i < 512; i += 256) bcur[i] = 0;
    }
    int t = blockIdx.x * blockDim.x + threadIdx.x;
    if (t < 128 * 128) {
        int n = t >> 7, k = t & 127;
        float s = 0.f;
        if (n < 40) {
            const float* W0 = W + (size_t)k * U;
            const float* W2 = W + (size_t)2 * D * U + (size_t)k * U;
            for (int u = 0; u < U; ++u) s += (W0[u] - W2[u]) * Wd[u * C + n];
        } else if (n < 80) {
            const float* W1 = W + (size_t)D * U + (size_t)k * U;
            for (int u = 0; u < U; ++u) s -= W1[u] * Wd[u * C + (n - 40)];
        } else if (n < 120) {
            const float* W2 = W + (size_t)2 * D * U + (size_t)k * U;
            for (int u = 0; u < U; ++u) s += 2.f * W2[u] * Wd[u * C + (n - 80)];
        }
        Gbf[n * GK + k] = (unsigned short)f2bf(s);
    } else if (t < 128 * 128 + C) {
        int c = t - 128 * 128;
        float s = bd[c];
        for (int u = 0; u < U; ++u) s += b[u] * Wd[u * C + c];
        bc[c] = s;
    }
}

// Pass C: two-level counting scatter into per-bucket contiguous regions.
// Records packed to int2: w0 = src(17b) | dst_low8 << 24 ; w1 = ew bits.
__global__ __launch_bounds__(TPB) void bucket_scatter(const int* __restrict__ src,
                                                      const int* __restrict__ dst,
                                                      const float* __restrict__ ew,
                                                      int* __restrict__ bcur,
                                                      int2* __restrict__ bbuf2) {
    __shared__ int hist[NB];
    __shared__ int base[NB];
    int t = threadIdx.x;
    for (int i = t; i < NB; i += TPB) hist[i] = 0;
    __syncthreads();

    size_t e0 = (size_t)blockIdx.x * (TPB * EPB);
    int ms[EPB], md[EPB], mw[EPB], mr[EPB];
#pragma unroll
    for (int k = 0; k < EPB; ++k) {
        size_t e = e0 + (size_t)k * TPB + t;
        if (e < E) {
            ms[k] = src[e];
            md[k] = dst[e];
            mw[k] = __float_as_int(ew[e]);
            mr[k] = atomicAdd(&hist[md[k] >> 8], 1);
        } else {
            md[k] = -1;
        }
    }
    __syncthreads();
    for (int i = t; i < NB; i += TPB) {
        int c = hist[i];
        base[i] = c ? atomicAdd(&bcur[i], c) : 0;
    }
    __syncthreads();
#pragma unroll
    for (int k = 0; k < EPB; ++k) {
        if (md[k] >= 0) {
            int bkt = md[k] >> 8;
            int slot = base[bkt] + mr[k];
            if (slot < CAP)
                bbuf2[(size_t)bkt * CAP + slot] =
                    make_int2(ms[k] | ((md[k] & 255) << 24), mw[k]);
        }
    }
}

// Fused kernel: blocks [0, NB) run csr_build; blocks [NB, NB+PROJ_BLOCKS) run
// proj_mfma. The two phases are independent (csr consumes bucket_scatter's
// output; proj consumes only x and Gbf) and previously ran serially.
__global__ __launch_bounds__(256) void csr_and_proj(
    const int* __restrict__ bcur, const int2* __restrict__ bbuf2,
    int2* __restrict__ meta, int2* __restrict__ csr,
    const float* __restrict__ X, const unsigned* __restrict__ Gu,
    const float* __restrict__ bc, float* __restrict__ out,
    float* __restrict__ P1, unsigned short* __restrict__ P2B16) {
    __shared__ __align__(16) unsigned char smem[SMEM_PROJ];
    int t = threadIdx.x;

    if (blockIdx.x < NB) {
        // ---- csr_build: LDS-only slotting + weighted-degree; zero-pad to mult of 16
        int* lcur = (int*)smem;
        float* lw = (float*)(smem + 1024);
        int b = blockIdx.x;
        lcur[t] = 0;
        lw[t] = 0.f;
        __syncthreads();
        int cnt = min(bcur[b], CAP);
        for (int i = t; i < cnt; i += 256) {
            int2 r = bbuf2[(size_t)b * CAP + i];
            int idx = ((unsigned)r.x) >> 24;
            int srcn = r.x & 0x00FFFFFF;
            int slot = atomicAdd(&lcur[idx], 1);
            atomicAdd(&lw[idx], __int_as_float(r.y));
            if (slot < SLOTS)
                csr[(((size_t)(b << 8) + idx) << 6) + slot] = make_int2(srcn, r.y);
        }
        __syncthreads();
        int node = (b << 8) + t;
        if (node < N) {
            int c = min(lcur[t], SLOTS);
            float rdeg = 1.f / fmaxf(lw[t], 1e-12f);
            meta[node] = make_int2(c, __float_as_int(rdeg));
            int padded = min((c + 15) & ~15, SLOTS);
            for (int s = c; s < padded; ++s)
                csr[((size_t)node << 6) + s] = make_int2(0, 0);
        }
        return;
    }

    // ---- proj_mfma: [64x128] @ [128x120] bf16 MFMA GEMM per 64-row tile
    int rb = blockIdx.x - NB;
    unsigned short* a_s = (unsigned short*)smem;                     // 64*GK
    unsigned short* g_s = (unsigned short*)(smem + 64 * GK * 2);     // 128*GK
    float* bc_s = (float*)(smem + 64 * GK * 2 + 128 * GK * 2);       // C

    unsigned* gsu = (unsigned*)g_s;
    for (int i = t; i < 128 * GK / 2; i += 256) gsu[i] = Gu[i];
    if (t < C) bc_s[t] = bc[t];

#pragma unroll
    for (int i = 0; i < 8; ++i) {
        int idx = i * 256 + t;
        int row = idx >> 5, kq = idx & 31;
        size_t grow = (size_t)rb * 64 + row;
        float4 v = (grow < N) ? ((const float4*)X)[grow * 32 + kq]
                              : make_float4(0.f, 0.f, 0.f, 0.f);
        unsigned* dstp = (unsigned*)(a_s + row * GK + kq * 4);
        dstp[0] = pack_bf2(v.x, v.y);
        dstp[1] = pack_bf2(v.z, v.w);
    }
    __syncthreads();

    int w = t >> 6, l = t & 63;
    int lr = l & 15, lh = l >> 4;

    bf16x8 afr[4];
#pragma unroll
    for (int ks = 0; ks < 4; ++ks)
        afr[ks] = *(const bf16x8*)(a_s + (w * 16 + lr) * GK + ks * 32 + lh * 8);

    f32x4 acc[8];
#pragma unroll
    for (int tt = 0; tt < 8; ++tt) {
        acc[tt] = (f32x4){0.f, 0.f, 0.f, 0.f};
#pragma unroll
        for (int ks = 0; ks < 4; ++ks) {
            bf16x8 bfr = *(const bf16x8*)(g_s + (tt * 16 + lr) * GK + ks * 32 + lh * 8);
            acc[tt] = __builtin_amdgcn_mfma_f32_16x16x32_bf16(afr[ks], bfr, acc[tt], 0, 0, 0);
        }
    }

#pragma unroll
    for (int tt = 0; tt < 8; ++tt) {
        int gcol = tt * 16 + lr;
#pragma unroll
        for (int r = 0; r < 4; ++r) {
            size_t grow = (size_t)rb * 64 + w * 16 + lh * 4 + r;
            if (grow >= N) continue;
            float v = acc[tt][r];
            if (gcol < 40) {
                out[grow * C + gcol] = v + bc_s[gcol];
            } else if (gcol < 80) {
                P1[grow * C + (gcol - 40)] = v;
            } else if (gcol < 120) {
                P2B16[grow * 64 + (gcol - 80)] = (unsigned short)f2bf(v);
            }
        }
    }
}

// gather SpMM v4: scalar metadata + precomputed rdeg + 16-edge batches.
//   Y[n] = Add[n] + rdeg * sum_e w_e * Xg[src_e]
// One wave/node. CSR rows zero-padded to multiple of 16 -> no tail masking.
// Lanes 0-31 handle edges j0..j0+7, lanes 32-63 handle j0+8..j0+15; combined
// via shfl_xor(32). OUT_BF writes the full 128B padded row -> no RMW.
template <bool OUT_BF>
__global__ __launch_bounds__(256) void spmm40v4(const int2* __restrict__ meta,
                                                const int2* __restrict__ csr,
                                                const unsigned* __restrict__ Xg,
                                                const float* __restrict__ Add,
                                                void* __restrict__ Yv) {
    int wid = (blockIdx.x * blockDim.x + threadIdx.x) >> 6;
    if (wid >= N) return;
    int uw = __builtin_amdgcn_readfirstlane(wid);
    int2 m = meta[uw];                     // uniform -> s_load_dwordx2
    int c = m.x;
    float rdeg = __int_as_float(m.y);
    const int2* __restrict__ row = csr + ((size_t)uw << 6);
    int lane = threadIdx.x & 63;
    bool hi = lane >= 32;
    unsigned voff = (unsigned)(lane & 31); // word index within padded 32-word row

    float2 ad = make_float2(0.f, 0.f);
    if (lane < C2) ad = ((const float2*)Add)[(size_t)wid * C2 + lane];

    float2 acc = make_float2(0.f, 0.f);
    for (int j0 = 0; j0 < c; j0 += 16) {
        unsigned va[8];
        float wa[8];
#pragma unroll
        for (int k = 0; k < 8; ++k) {
            int2 a = row[j0 + k];          // uniform -> s_load
            int2 b = row[j0 + 8 + k];
            int col = hi ? b.x : a.x;
            wa[k] = __int_as_float(hi ? b.y : a.y);
            va[k] = Xg[((unsigned)col << 5) + voff];  // SGPR base + 32-bit voffset
        }
#pragma unroll
        for (int k = 0; k < 8; ++k) {
            float2 v = unpack_bf2(va[k]);
            acc.x = fmaf(wa[k], v.x, acc.x);
            acc.y = fmaf(wa[k], v.y, acc.y);
        }
    }
    acc.x += __shfl_xor(acc.x, 32);
    acc.y += __shfl_xor(acc.y, 32);

    if (OUT_BF) {
        if (lane < 32) {
            unsigned o = 0u;
            if (lane < C2)
                o = pack_bf2(fmaf(acc.x, rdeg, ad.x), fmaf(acc.y, rdeg, ad.y));
            ((unsigned*)Yv)[((size_t)wid << 5) + lane] = o;  // full 128B row, no RMW
        }
    } else {
        if (lane < C2) {
            ((float2*)Yv)[(size_t)wid * C2 + lane] =
                make_float2(fmaf(acc.x, rdeg, ad.x), fmaf(acc.y, rdeg, ad.y));
        }
    }
}

extern "C" void kernel_launch(void* const* d_in, const int* in_sizes, int n_in,
                              void* d_out, int out_size, void* d_ws, size_t ws_size,
                              hipStream_t stream) {
    const float* x = (const float*)d_in[0];
    const int* ei = (const int*)d_in[1];   // (2, E): src = ei, dst = ei + E
    const float* ew = (const float*)d_in[2];
    const float* W = (const float*)d_in[3];
    const float* b = (const float*)d_in[4];
    const float* Wd = (const float*)d_in[5];
    const float* bd = (const float*)d_in[6];
    float* out = (float*)d_out;

    const int* src = ei;
    const int* dst = ei + E;

    float* ws = (float*)d_ws;
    int* bcur = (int*)(ws + OFF_BCUR);
    int2* meta = (int2*)(ws + OFF_META);
    int2* csr = (int2*)(ws + OFF_CSR);
    int2* bbuf2 = (int2*)(ws + OFF_BBUF);
    float* P1 = ws + OFF_P1;
    unsigned* P2B = (unsigned*)(ws + OFF_P2B);
    unsigned* Rbf = (unsigned*)(ws + OFF_RBF);
    unsigned short* Gbf = (unsigned short*)(ws + OFF_GBF);
    float* bc = ws + OFF_BC;

    // prep: fold weights + zero bucket cursors (no memset dispatch)
    prep_weights<<<(128 * 128 + C + 255) / 256, 256, 0, stream>>>(W, b, Wd, bd, Gbf, bc, bcur);

    // two-level counting sort, packed int2 records
    bucket_scatter<<<(E + TPB * EPB - 1) / (TPB * EPB), TPB, 0, stream>>>(src, dst, ew, bcur, bbuf2);

    // fused: csr_build (391 blocks) || proj_mfma (1563 blocks)
    csr_and_proj<<<NB + PROJ_BLOCKS, 256, 0, stream>>>(bcur, bbuf2, meta, csr, x,
                                                       (const unsigned*)Gbf, bc, out, P1,
                                                       (unsigned short*)P2B);

    // Rbf = bf16(P1 + A_hat @ P2)
    spmm40v4<true><<<((size_t)N * 64 + 255) / 256, 256, 0, stream>>>(meta, csr, P2B, P1, Rbf);
    // out += A_hat @ R
    spmm40v4<false><<<((size_t)N * 64 + 255) / 256, 256, 0, stream>>>(meta, csr, Rbf, out, out);
}